// Round 1
// baseline (1556.445 us; speedup 1.0000x reference)
//
#include <hip/hip_runtime.h>

// GCN encoder: 3x GCNConv (sym-norm, self-loops) + 2x BatchNorm(train)+ReLU+residual.
// N=50000, E=800000, IN=HID=128, OUT=64. All fp32; edge_index as int32 per harness.
//
// BN bias-cancel: conv bias b1/b2 vanishes inside BatchNorm (mean-subtracted),
// so only b3 is applied (folded into the self-loop init of the output layer).

#define BN_EPS 1e-5f

// ---------- degree / normalization ----------
__global__ void k_init_deg(float* __restrict__ deg, int n) {
    int i = blockIdx.x * 256 + threadIdx.x;
    if (i < n) deg[i] = 1.0f;  // self-loop contributes 1
}

__global__ void k_edge_deg(float* __restrict__ deg, const int* __restrict__ dst, int e) {
    int i = blockIdx.x * 256 + threadIdx.x;
    if (i < e) atomicAdd(&deg[dst[i]], 1.0f);
}

__global__ void k_dinv(float* __restrict__ deg, int n) {
    int i = blockIdx.x * 256 + threadIdx.x;
    if (i < n) deg[i] = rsqrtf(deg[i]);  // deg >= 1 always (self-loop)
}

// ---------- GEMMs (fp32, naive; W cached in L1/L2 — 64KB) ----------
// C[n,128] = A[n,128] @ W[128,128]; 2 rows per 256-thread block
__global__ void k_gemm128(const float* __restrict__ A, const float* __restrict__ W,
                          float* __restrict__ C, int n) {
    int row = blockIdx.x * 2 + (threadIdx.x >> 7);
    int col = threadIdx.x & 127;
    if (row >= n) return;
    const float* a = A + (size_t)row * 128;
    float acc = 0.f;
#pragma unroll 8
    for (int k = 0; k < 128; ++k) acc = fmaf(a[k], W[k * 128 + col], acc);
    C[(size_t)row * 128 + col] = acc;
}

// C[n,64] = A[n,128] @ W[128,64]; 4 rows per 256-thread block
__global__ void k_gemm64(const float* __restrict__ A, const float* __restrict__ W,
                         float* __restrict__ C, int n) {
    int row = blockIdx.x * 4 + (threadIdx.x >> 6);
    int col = threadIdx.x & 63;
    if (row >= n) return;
    const float* a = A + (size_t)row * 128;
    float acc = 0.f;
#pragma unroll 8
    for (int k = 0; k < 128; ++k) acc = fmaf(a[k], W[k * 64 + col], acc);
    C[(size_t)row * 64 + col] = acc;
}

// ---------- aggregation ----------
// agg[i,f] = xw[i,f] * dinv[i]^2   (self-loop term; also zero-initializes agg)
__global__ void k_self128(float* __restrict__ agg, const float* __restrict__ xw,
                          const float* __restrict__ dinv, int n) {
    int gid = blockIdx.x * 256 + threadIdx.x;
    if (gid >= n * 128) return;
    float dv = dinv[gid >> 7];
    agg[gid] = xw[gid] * dv * dv;
}

// agg[dst,f] += xw[src,f] * dinv[src]*dinv[dst]; thread = (edge, feature)
__global__ void k_scatter128(float* __restrict__ agg, const float* __restrict__ xw,
                             const int* __restrict__ src, const int* __restrict__ dst,
                             const float* __restrict__ dinv, int e) {
    int gid = blockIdx.x * 256 + threadIdx.x;
    if (gid >= e * 128) return;
    int ed = gid >> 7, f = gid & 127;
    int s = src[ed], d = dst[ed];     // wave-uniform loads
    float w = dinv[s] * dinv[d];
    atomicAdd(&agg[(size_t)d * 128 + f], xw[(size_t)s * 128 + f] * w);
}

// out[i,f] = xw[i,f]*dinv[i]^2 + b[f]  (output layer: self-loop + bias, direct to d_out)
__global__ void k_self64_bias(float* __restrict__ out, const float* __restrict__ xw,
                              const float* __restrict__ dinv, const float* __restrict__ b,
                              int n) {
    int gid = blockIdx.x * 256 + threadIdx.x;
    if (gid >= n * 64) return;
    int i = gid >> 6, f = gid & 63;
    float dv = dinv[i];
    out[gid] = xw[gid] * dv * dv + b[f];
}

__global__ void k_scatter64(float* __restrict__ out, const float* __restrict__ xw,
                            const int* __restrict__ src, const int* __restrict__ dst,
                            const float* __restrict__ dinv, int e) {
    int gid = blockIdx.x * 256 + threadIdx.x;
    if (gid >= e * 64) return;
    int ed = gid >> 6, f = gid & 63;
    int s = src[ed], d = dst[ed];
    float w = dinv[s] * dinv[d];
    atomicAdd(&out[(size_t)d * 64 + f], xw[(size_t)s * 64 + f] * w);
}

// ---------- batch-norm statistics ----------
// per-column sum & sumsq over N rows (128 cols); 2 row-streams per block
__global__ void k_stats(const float* __restrict__ h, float* __restrict__ gsum,
                        float* __restrict__ gsq, int n) {
    int c = threadIdx.x & 127;
    int half = threadIdx.x >> 7;
    float s = 0.f, s2 = 0.f;
    for (int r = blockIdx.x * 2 + half; r < n; r += gridDim.x * 2) {
        float v = h[(size_t)r * 128 + c];
        s += v; s2 += v * v;
    }
    __shared__ float ls[256], ls2[256];
    ls[threadIdx.x] = s; ls2[threadIdx.x] = s2;
    __syncthreads();
    if (threadIdx.x < 128) {
        atomicAdd(&gsum[c], ls[threadIdx.x] + ls[threadIdx.x + 128]);
        atomicAdd(&gsq[c],  ls2[threadIdx.x] + ls2[threadIdx.x + 128]);
    }
}

__global__ void k_finalize(const float* __restrict__ gsum, const float* __restrict__ gsq,
                           const float* __restrict__ gamma, const float* __restrict__ beta,
                           float* __restrict__ scale, float* __restrict__ shift, float inv_n) {
    int c = threadIdx.x;  // 128 threads
    float m = gsum[c] * inv_n;
    float v = gsq[c] * inv_n - m * m;
    float sc = gamma[c] * rsqrtf(v + BN_EPS);
    scale[c] = sc;
    shift[c] = beta[c] - m * sc;
}

// h[i,c] = relu(agg[i,c]*scale[c] + shift[c]) + res[i,c]
__global__ void k_bnrelu_res(float* __restrict__ out, const float* __restrict__ agg,
                             const float* __restrict__ scale, const float* __restrict__ shift,
                             const float* __restrict__ res, int total) {
    int gid = blockIdx.x * 256 + threadIdx.x;
    if (gid >= total) return;
    int c = gid & 127;
    float v = fmaf(agg[gid], scale[c], shift[c]);
    v = v > 0.f ? v : 0.f;
    out[gid] = v + res[gid];
}

extern "C" void kernel_launch(void* const* d_in, const int* in_sizes, int n_in,
                              void* d_out, int out_size, void* d_ws, size_t ws_size,
                              hipStream_t stream) {
    const float* x   = (const float*)d_in[0];
    const int*   ei  = (const int*)d_in[1];
    const float* W1  = (const float*)d_in[2];
    // b1 = d_in[3]  — cancelled by BN
    const float* W2  = (const float*)d_in[4];
    // b2 = d_in[5]  — cancelled by BN
    const float* W3  = (const float*)d_in[6];
    const float* b3  = (const float*)d_in[7];
    const float* g1  = (const float*)d_in[8];
    const float* be1 = (const float*)d_in[9];
    const float* g2  = (const float*)d_in[10];
    const float* be2 = (const float*)d_in[11];
    float* out = (float*)d_out;

    const int N = in_sizes[0] / 128;
    const int E = in_sizes[1] / 2;
    const int* src = ei;
    const int* dst = ei + E;

    // workspace layout (floats)
    float* ws    = (float*)d_ws;
    float* dinv  = ws;                          // N   (deg, then dinv in place)
    float* xw    = dinv + N;                    // N*128
    float* agg   = xw + (size_t)N * 128;        // N*128 (layer agg; layer-2 output in place)
    float* h1    = agg + (size_t)N * 128;       // N*128
    float* gsum  = h1 + (size_t)N * 128;        // 128
    float* gsq   = gsum + 128;                  // 128
    float* scale = gsq + 128;                   // 128
    float* shift = scale + 128;                 // 128

    const int B = 256;
    const int gN    = (N + B - 1) / B;
    const int gE    = (E + B - 1) / B;
    const int gNF   = (N * 128 + B - 1) / B;
    const int gEF   = (E * 128 + B - 1) / B;   // 400000 blocks
    const int gNO   = (N * 64 + B - 1) / B;
    const int gEO   = (E * 64 + B - 1) / B;
    const float inv_n = 1.0f / (float)N;

    // normalization coefficients
    k_init_deg<<<gN, B, 0, stream>>>(dinv, N);
    k_edge_deg<<<gE, B, 0, stream>>>(dinv, dst, E);
    k_dinv<<<gN, B, 0, stream>>>(dinv, N);

    // ---- layer 1: h1 = relu(bn(conv(x, W1))) + x ----
    k_gemm128<<<(N + 1) / 2, B, 0, stream>>>(x, W1, xw, N);
    k_self128<<<gNF, B, 0, stream>>>(agg, xw, dinv, N);
    k_scatter128<<<gEF, B, 0, stream>>>(agg, xw, src, dst, dinv, E);
    hipMemsetAsync(gsum, 0, 2 * 128 * sizeof(float), stream);
    k_stats<<<512, B, 0, stream>>>(agg, gsum, gsq, N);
    k_finalize<<<1, 128, 0, stream>>>(gsum, gsq, g1, be1, scale, shift, inv_n);
    k_bnrelu_res<<<gNF, B, 0, stream>>>(h1, agg, scale, shift, x, N * 128);

    // ---- layer 2: h2 = relu(bn(conv(h1, W2))) + h1  (h2 overwrites agg in place) ----
    k_gemm128<<<(N + 1) / 2, B, 0, stream>>>(h1, W2, xw, N);
    k_self128<<<gNF, B, 0, stream>>>(agg, xw, dinv, N);
    k_scatter128<<<gEF, B, 0, stream>>>(agg, xw, src, dst, dinv, E);
    hipMemsetAsync(gsum, 0, 2 * 128 * sizeof(float), stream);
    k_stats<<<512, B, 0, stream>>>(agg, gsum, gsq, N);
    k_finalize<<<1, 128, 0, stream>>>(gsum, gsq, g2, be2, scale, shift, inv_n);
    k_bnrelu_res<<<gNF, B, 0, stream>>>(agg, agg, scale, shift, h1, N * 128);

    // ---- output layer: out = conv(h2, W3) + b3 ----
    k_gemm64<<<(N + 3) / 4, B, 0, stream>>>(agg, W3, xw, N);
    k_self64_bias<<<gNO, B, 0, stream>>>(out, xw, dinv, b3, N);
    k_scatter64<<<gEO, B, 0, stream>>>(out, xw, src, dst, dinv, E);
}

// Round 2
// 979.095 us; speedup vs baseline: 1.5897x; 1.5897x over previous
//
#include <hip/hip_runtime.h>

// GCN encoder: 3x GCNConv (sym-norm, self-loops) + 2x BatchNorm(train)+ReLU+residual.
// N=50000, E=800000, IN=HID=128, OUT=64. fp32; edge_index int32 (harness casts int64->int32 layout? per harness: integer -> const int*).
//
// R2: scatter-atomics (400MB HBM write-through per layer) replaced by CSR gather.
//     dinv[src] folded into GEMM epilogue (xs = (A@W)*dinv[row]); aggregation is
//     agg[d] = dinv[d] * (xs[d] + sum xs[src]) — no fp32 atomics, one write/row.
// BN bias-cancel: b1/b2 vanish inside BatchNorm; only b3 applied (gather64 epilogue).

#define BN_EPS 1e-5f

// ---------- CSR build ----------
__global__ void k_cnt_deg(int* __restrict__ cnt, const int* __restrict__ dst, int e) {
    int i = blockIdx.x * 256 + threadIdx.x;
    if (i < e) atomicAdd(&cnt[dst[i]], 1);
}

// single-block exclusive scan of cnt[0..n) -> rs[0..n]
__global__ void k_scan(const int* __restrict__ cnt, int* __restrict__ rs, int n) {
    __shared__ int part[256];
    int t = threadIdx.x;
    int L = (n + 255) / 256;
    int lo = min(t * L, n), hi = min(lo + L, n);
    int s = 0;
    for (int i = lo; i < hi; ++i) s += cnt[i];
    part[t] = s;
    __syncthreads();
    if (t == 0) {
        int acc = 0;
        for (int i = 0; i < 256; ++i) { int v = part[i]; part[i] = acc; acc += v; }
    }
    __syncthreads();
    int acc = part[t];
    for (int i = lo; i < hi; ++i) { rs[i] = acc; acc += cnt[i]; }
    if (t == 255) rs[n] = acc;
}

__global__ void k_dinv_from_cnt(float* __restrict__ dinv, const int* __restrict__ cnt, int n) {
    int i = blockIdx.x * 256 + threadIdx.x;
    if (i < n) dinv[i] = rsqrtf((float)(cnt[i] + 1));  // +1 self-loop
}

__global__ void k_bucket(const int* __restrict__ src, const int* __restrict__ dst,
                         int* __restrict__ cursor, int* __restrict__ eb, int e) {
    int i = blockIdx.x * 256 + threadIdx.x;
    if (i < e) {
        int d = dst[i];
        int p = atomicAdd(&cursor[d], 1);
        eb[p] = src[i];
    }
}

// ---------- GEMMs (fp32 naive; W is 64KB, L1/L2-resident). Epilogue scales by dinv[row]. ----------
__global__ void k_gemm128(const float* __restrict__ A, const float* __restrict__ W,
                          float* __restrict__ xs, const float* __restrict__ dinv, int n) {
    int row = blockIdx.x * 2 + (threadIdx.x >> 7);
    int col = threadIdx.x & 127;
    if (row >= n) return;
    const float* a = A + (size_t)row * 128;
    float acc = 0.f;
#pragma unroll 8
    for (int k = 0; k < 128; ++k) acc = fmaf(a[k], W[k * 128 + col], acc);
    xs[(size_t)row * 128 + col] = acc * dinv[row];
}

__global__ void k_gemm64(const float* __restrict__ A, const float* __restrict__ W,
                         float* __restrict__ xs, const float* __restrict__ dinv, int n) {
    int row = blockIdx.x * 4 + (threadIdx.x >> 6);
    int col = threadIdx.x & 63;
    if (row >= n) return;
    const float* a = A + (size_t)row * 128;
    float acc = 0.f;
#pragma unroll 8
    for (int k = 0; k < 128; ++k) acc = fmaf(a[k], W[k * 64 + col], acc);
    xs[(size_t)row * 64 + col] = acc * dinv[row];
}

// ---------- CSR gather aggregation ----------
// agg[d,:] = dinv[d] * (xs[d,:] + sum_{e in [rs[d],rs[d+1])} xs[eb[e],:])
// 32 lanes x float4 per node (128 feat); 8 nodes per 256-thread block.
__global__ void k_gather128(float* __restrict__ agg, const float* __restrict__ xs,
                            const int* __restrict__ rs, const int* __restrict__ eb,
                            const float* __restrict__ dinv, int n) {
    int node = blockIdx.x * 8 + (threadIdx.x >> 5);
    int lane = threadIdx.x & 31;
    if (node >= n) return;
    const float4* xv = (const float4*)xs;
    float4 v = xv[(size_t)node * 32 + lane];  // self-loop term (xs already has dinv[src] factor)
    float ax = v.x, ay = v.y, az = v.z, aw = v.w;
    int b = rs[node], e = rs[node + 1];
    for (int i = b; i < e; ++i) {
        int s = eb[i];  // wave-uniform within node-group
        float4 u = xv[(size_t)s * 32 + lane];
        ax += u.x; ay += u.y; az += u.z; aw += u.w;
    }
    float dv = dinv[node];
    float4 o; o.x = ax * dv; o.y = ay * dv; o.z = az * dv; o.w = aw * dv;
    ((float4*)agg)[(size_t)node * 32 + lane] = o;
}

// 16 lanes x float4 per node (64 feat); 16 nodes per block. Adds bias b3 (output layer).
__global__ void k_gather64_bias(float* __restrict__ out, const float* __restrict__ xs,
                                const int* __restrict__ rs, const int* __restrict__ eb,
                                const float* __restrict__ dinv, const float* __restrict__ bias,
                                int n) {
    int node = blockIdx.x * 16 + (threadIdx.x >> 4);
    int lane = threadIdx.x & 15;
    if (node >= n) return;
    const float4* xv = (const float4*)xs;
    float4 v = xv[(size_t)node * 16 + lane];
    float ax = v.x, ay = v.y, az = v.z, aw = v.w;
    int b = rs[node], e = rs[node + 1];
    for (int i = b; i < e; ++i) {
        int s = eb[i];
        float4 u = xv[(size_t)s * 16 + lane];
        ax += u.x; ay += u.y; az += u.z; aw += u.w;
    }
    float dv = dinv[node];
    const float4* bv = (const float4*)bias;
    float4 bb = bv[lane];
    float4 o;
    o.x = ax * dv + bb.x; o.y = ay * dv + bb.y; o.z = az * dv + bb.z; o.w = aw * dv + bb.w;
    ((float4*)out)[(size_t)node * 16 + lane] = o;
}

// ---------- batch-norm statistics ----------
__global__ void k_stats(const float* __restrict__ h, float* __restrict__ gsum,
                        float* __restrict__ gsq, int n) {
    int c = threadIdx.x & 127;
    int half = threadIdx.x >> 7;
    float s = 0.f, s2 = 0.f;
    for (int r = blockIdx.x * 2 + half; r < n; r += gridDim.x * 2) {
        float v = h[(size_t)r * 128 + c];
        s += v; s2 += v * v;
    }
    __shared__ float ls[256], ls2[256];
    ls[threadIdx.x] = s; ls2[threadIdx.x] = s2;
    __syncthreads();
    if (threadIdx.x < 128) {
        atomicAdd(&gsum[c], ls[threadIdx.x] + ls[threadIdx.x + 128]);
        atomicAdd(&gsq[c],  ls2[threadIdx.x] + ls2[threadIdx.x + 128]);
    }
}

__global__ void k_finalize(const float* __restrict__ gsum, const float* __restrict__ gsq,
                           const float* __restrict__ gamma, const float* __restrict__ beta,
                           float* __restrict__ scale, float* __restrict__ shift, float inv_n) {
    int c = threadIdx.x;  // 128 threads
    float m = gsum[c] * inv_n;
    float v = gsq[c] * inv_n - m * m;
    float sc = gamma[c] * rsqrtf(v + BN_EPS);
    scale[c] = sc;
    shift[c] = beta[c] - m * sc;
}

// h[i,c] = relu(agg[i,c]*scale[c] + shift[c]) + res[i,c]
__global__ void k_bnrelu_res(float* __restrict__ out, const float* __restrict__ agg,
                             const float* __restrict__ scale, const float* __restrict__ shift,
                             const float* __restrict__ res, int total) {
    int gid = blockIdx.x * 256 + threadIdx.x;
    if (gid >= total) return;
    int c = gid & 127;
    float v = fmaf(agg[gid], scale[c], shift[c]);
    v = v > 0.f ? v : 0.f;
    out[gid] = v + res[gid];
}

extern "C" void kernel_launch(void* const* d_in, const int* in_sizes, int n_in,
                              void* d_out, int out_size, void* d_ws, size_t ws_size,
                              hipStream_t stream) {
    const float* x   = (const float*)d_in[0];
    const int*   ei  = (const int*)d_in[1];
    const float* W1  = (const float*)d_in[2];
    const float* W2  = (const float*)d_in[4];
    const float* W3  = (const float*)d_in[6];
    const float* b3  = (const float*)d_in[7];
    const float* g1  = (const float*)d_in[8];
    const float* be1 = (const float*)d_in[9];
    const float* g2  = (const float*)d_in[10];
    const float* be2 = (const float*)d_in[11];
    float* out = (float*)d_out;

    const int N = in_sizes[0] / 128;
    const int E = in_sizes[1] / 2;
    const int* src = ei;
    const int* dst = ei + E;

    // workspace layout (16B-aligned segments)
    char* p = (char*)d_ws;
    float* dinv  = (float*)p;            p += (size_t)N * 4;            // N
    float* xs    = (float*)p;            p += (size_t)N * 128 * 4;      // N*128
    float* agg   = (float*)p;            p += (size_t)N * 128 * 4;      // N*128
    float* h1    = (float*)p;            p += (size_t)N * 128 * 4;      // N*128
    float* gsum  = (float*)p;            p += 128 * 4;
    float* gsq   = (float*)p;            p += 128 * 4;
    float* scale = (float*)p;            p += 128 * 4;
    float* shift = (float*)p;            p += 128 * 4;
    int*   cnt   = (int*)p;              p += (size_t)N * 4;
    int*   rs    = (int*)p;              p += (size_t)(N + 16) * 4;     // N+1 (padded)
    int*   cursor= (int*)p;              p += (size_t)N * 4;
    int*   eb    = (int*)p;              p += (size_t)E * 4;

    const int B = 256;
    const int gE  = (E + B - 1) / B;
    const int gN  = (N + B - 1) / B;
    const int gNF = (N * 128 + B - 1) / B;
    const float inv_n = 1.0f / (float)N;

    // ---- CSR build + normalization ----
    hipMemsetAsync(cnt, 0, (size_t)N * 4, stream);
    k_cnt_deg<<<gE, B, 0, stream>>>(cnt, dst, E);
    k_scan<<<1, 256, 0, stream>>>(cnt, rs, N);
    k_dinv_from_cnt<<<gN, B, 0, stream>>>(dinv, cnt, N);
    hipMemcpyAsync(cursor, rs, (size_t)N * 4, hipMemcpyDeviceToDevice, stream);
    k_bucket<<<gE, B, 0, stream>>>(src, dst, cursor, eb, E);

    // ---- layer 1: h1 = relu(bn(agg)) + x ----
    k_gemm128<<<(N + 1) / 2, B, 0, stream>>>(x, W1, xs, dinv, N);
    k_gather128<<<(N + 7) / 8, B, 0, stream>>>(agg, xs, rs, eb, dinv, N);
    hipMemsetAsync(gsum, 0, 2 * 128 * 4, stream);
    k_stats<<<512, B, 0, stream>>>(agg, gsum, gsq, N);
    k_finalize<<<1, 128, 0, stream>>>(gsum, gsq, g1, be1, scale, shift, inv_n);
    k_bnrelu_res<<<gNF, B, 0, stream>>>(h1, agg, scale, shift, x, N * 128);

    // ---- layer 2: h2 = relu(bn(agg)) + h1  (h2 overwrites agg in place) ----
    k_gemm128<<<(N + 1) / 2, B, 0, stream>>>(h1, W2, xs, dinv, N);
    k_gather128<<<(N + 7) / 8, B, 0, stream>>>(agg, xs, rs, eb, dinv, N);
    hipMemsetAsync(gsum, 0, 2 * 128 * 4, stream);
    k_stats<<<512, B, 0, stream>>>(agg, gsum, gsq, N);
    k_finalize<<<1, 128, 0, stream>>>(gsum, gsq, g2, be2, scale, shift, inv_n);
    k_bnrelu_res<<<gNF, B, 0, stream>>>(agg, agg, scale, shift, h1, N * 128);

    // ---- output layer: out = gather(xs3) + b3 ----
    k_gemm64<<<(N + 3) / 4, B, 0, stream>>>(agg, W3, xs, dinv, N);
    k_gather64_bias<<<(N + 15) / 16, B, 0, stream>>>(out, xs, rs, eb, dinv, b3, N);
}

// Round 3
// 617.325 us; speedup vs baseline: 2.5213x; 1.5860x over previous
//
#include <hip/hip_runtime.h>

// GCN encoder: 3x GCNConv (sym-norm, self-loops) + 2x BatchNorm(train)+ReLU+residual.
// N=50000, E=800000, IN=HID=128, OUT=64. fp32; edge_index int32.
//
// R2: CSR gather (no fp32 atomics), dinv folded into GEMM epilogue.
// R3: register-tiled GEMMs. 64-row tile/block, per-thread 4x8 (128-col) or 4x4
//     (64-col) register tile; W staged in LDS in 32-k chunks; A via global float4
//     (16-lane broadcast, L1-served). Naive version was 2 loads/FMA @ 15% VALUBusy.
// BN bias-cancel: b1/b2 vanish inside BatchNorm; only b3 applied.

#define BN_EPS 1e-5f

// ---------- CSR build ----------
__global__ void k_cnt_deg(int* __restrict__ cnt, const int* __restrict__ dst, int e) {
    int i = blockIdx.x * 256 + threadIdx.x;
    if (i < e) atomicAdd(&cnt[dst[i]], 1);
}

__global__ void k_scan(const int* __restrict__ cnt, int* __restrict__ rs, int n) {
    __shared__ int part[256];
    int t = threadIdx.x;
    int L = (n + 255) / 256;
    int lo = min(t * L, n), hi = min(lo + L, n);
    int s = 0;
    for (int i = lo; i < hi; ++i) s += cnt[i];
    part[t] = s;
    __syncthreads();
    if (t == 0) {
        int acc = 0;
        for (int i = 0; i < 256; ++i) { int v = part[i]; part[i] = acc; acc += v; }
    }
    __syncthreads();
    int acc = part[t];
    for (int i = lo; i < hi; ++i) { rs[i] = acc; acc += cnt[i]; }
    if (t == 255) rs[n] = acc;
}

__global__ void k_dinv_from_cnt(float* __restrict__ dinv, const int* __restrict__ cnt, int n) {
    int i = blockIdx.x * 256 + threadIdx.x;
    if (i < n) dinv[i] = rsqrtf((float)(cnt[i] + 1));  // +1 self-loop
}

__global__ void k_bucket(const int* __restrict__ src, const int* __restrict__ dst,
                         int* __restrict__ cursor, int* __restrict__ eb, int e) {
    int i = blockIdx.x * 256 + threadIdx.x;
    if (i < e) {
        int d = dst[i];
        int p = atomicAdd(&cursor[d], 1);
        eb[p] = src[i];
    }
}

// ---------- register-tiled GEMMs ----------
// C[n,128] = A[n,128] @ W[128,128], epilogue *dinv[row].
// Block: 64 rows. Thread (cg=t&15, rg=t>>4): rows rg*4..+3, cols {4cg..+3, 64+4cg..+3}.
__global__ __launch_bounds__(256) void k_gemm128_t(
        const float* __restrict__ A, const float* __restrict__ W,
        float* __restrict__ xs, const float* __restrict__ dinv, int n) {
    __shared__ float Wt[32][128];  // one 32-k chunk of W, 16 KB
    const int t  = threadIdx.x;
    const int cg = t & 15;
    const int rg = t >> 4;
    const int row0 = blockIdx.x * 64 + rg * 4;

    const float* a_r[4];
#pragma unroll
    for (int r = 0; r < 4; ++r) a_r[r] = A + (size_t)min(row0 + r, n - 1) * 128;

    float acc[4][8];
#pragma unroll
    for (int r = 0; r < 4; ++r)
#pragma unroll
        for (int c = 0; c < 8; ++c) acc[r][c] = 0.f;

    for (int kc = 0; kc < 4; ++kc) {
        // stage W rows kc*32..+31 (contiguous 4096 floats) -> LDS
        const float4* wsrc = (const float4*)(W + (size_t)kc * 32 * 128);
        float4* wdst = (float4*)&Wt[0][0];
#pragma unroll
        for (int i = 0; i < 4; ++i) wdst[t + 256 * i] = wsrc[t + 256 * i];
        __syncthreads();

#pragma unroll
        for (int k4 = 0; k4 < 8; ++k4) {
            float4 a[4];
#pragma unroll
            for (int r = 0; r < 4; ++r)
                a[r] = *(const float4*)(a_r[r] + kc * 32 + k4 * 4);
#pragma unroll
            for (int j = 0; j < 4; ++j) {
                const int k = k4 * 4 + j;
                float4 w0 = *(const float4*)&Wt[k][cg * 4];
                float4 w1 = *(const float4*)&Wt[k][64 + cg * 4];
#pragma unroll
                for (int r = 0; r < 4; ++r) {
                    const float av = (&a[r].x)[j];
                    acc[r][0] = fmaf(av, w0.x, acc[r][0]);
                    acc[r][1] = fmaf(av, w0.y, acc[r][1]);
                    acc[r][2] = fmaf(av, w0.z, acc[r][2]);
                    acc[r][3] = fmaf(av, w0.w, acc[r][3]);
                    acc[r][4] = fmaf(av, w1.x, acc[r][4]);
                    acc[r][5] = fmaf(av, w1.y, acc[r][5]);
                    acc[r][6] = fmaf(av, w1.z, acc[r][6]);
                    acc[r][7] = fmaf(av, w1.w, acc[r][7]);
                }
            }
        }
        __syncthreads();
    }

#pragma unroll
    for (int r = 0; r < 4; ++r) {
        const int row = row0 + r;
        if (row < n) {
            const float dv = dinv[row];
            float4 o0 = { acc[r][0] * dv, acc[r][1] * dv, acc[r][2] * dv, acc[r][3] * dv };
            float4 o1 = { acc[r][4] * dv, acc[r][5] * dv, acc[r][6] * dv, acc[r][7] * dv };
            *(float4*)(xs + (size_t)row * 128 + cg * 4) = o0;
            *(float4*)(xs + (size_t)row * 128 + 64 + cg * 4) = o1;
        }
    }
}

// C[n,64] = A[n,128] @ W[128,64], epilogue *dinv[row]. Per-thread 4x4 tile.
__global__ __launch_bounds__(256) void k_gemm64_t(
        const float* __restrict__ A, const float* __restrict__ W,
        float* __restrict__ xs, const float* __restrict__ dinv, int n) {
    __shared__ float Wt[32][64];  // 8 KB chunk
    const int t  = threadIdx.x;
    const int cg = t & 15;
    const int rg = t >> 4;
    const int row0 = blockIdx.x * 64 + rg * 4;

    const float* a_r[4];
#pragma unroll
    for (int r = 0; r < 4; ++r) a_r[r] = A + (size_t)min(row0 + r, n - 1) * 128;

    float acc[4][4];
#pragma unroll
    for (int r = 0; r < 4; ++r)
#pragma unroll
        for (int c = 0; c < 4; ++c) acc[r][c] = 0.f;

    for (int kc = 0; kc < 4; ++kc) {
        const float4* wsrc = (const float4*)(W + (size_t)kc * 32 * 64);
        float4* wdst = (float4*)&Wt[0][0];
#pragma unroll
        for (int i = 0; i < 2; ++i) wdst[t + 256 * i] = wsrc[t + 256 * i];
        __syncthreads();

#pragma unroll
        for (int k4 = 0; k4 < 8; ++k4) {
            float4 a[4];
#pragma unroll
            for (int r = 0; r < 4; ++r)
                a[r] = *(const float4*)(a_r[r] + kc * 32 + k4 * 4);
#pragma unroll
            for (int j = 0; j < 4; ++j) {
                const int k = k4 * 4 + j;
                float4 w = *(const float4*)&Wt[k][cg * 4];
#pragma unroll
                for (int r = 0; r < 4; ++r) {
                    const float av = (&a[r].x)[j];
                    acc[r][0] = fmaf(av, w.x, acc[r][0]);
                    acc[r][1] = fmaf(av, w.y, acc[r][1]);
                    acc[r][2] = fmaf(av, w.z, acc[r][2]);
                    acc[r][3] = fmaf(av, w.w, acc[r][3]);
                }
            }
        }
        __syncthreads();
    }

#pragma unroll
    for (int r = 0; r < 4; ++r) {
        const int row = row0 + r;
        if (row < n) {
            const float dv = dinv[row];
            float4 o = { acc[r][0] * dv, acc[r][1] * dv, acc[r][2] * dv, acc[r][3] * dv };
            *(float4*)(xs + (size_t)row * 64 + cg * 4) = o;
        }
    }
}

// ---------- CSR gather aggregation ----------
__global__ void k_gather128(float* __restrict__ agg, const float* __restrict__ xs,
                            const int* __restrict__ rs, const int* __restrict__ eb,
                            const float* __restrict__ dinv, int n) {
    int node = blockIdx.x * 8 + (threadIdx.x >> 5);
    int lane = threadIdx.x & 31;
    if (node >= n) return;
    const float4* xv = (const float4*)xs;
    float4 v = xv[(size_t)node * 32 + lane];
    float ax = v.x, ay = v.y, az = v.z, aw = v.w;
    int b = rs[node], e = rs[node + 1];
    for (int i = b; i < e; ++i) {
        int s = eb[i];
        float4 u = xv[(size_t)s * 32 + lane];
        ax += u.x; ay += u.y; az += u.z; aw += u.w;
    }
    float dv = dinv[node];
    float4 o; o.x = ax * dv; o.y = ay * dv; o.z = az * dv; o.w = aw * dv;
    ((float4*)agg)[(size_t)node * 32 + lane] = o;
}

__global__ void k_gather64_bias(float* __restrict__ out, const float* __restrict__ xs,
                                const int* __restrict__ rs, const int* __restrict__ eb,
                                const float* __restrict__ dinv, const float* __restrict__ bias,
                                int n) {
    int node = blockIdx.x * 16 + (threadIdx.x >> 4);
    int lane = threadIdx.x & 15;
    if (node >= n) return;
    const float4* xv = (const float4*)xs;
    float4 v = xv[(size_t)node * 16 + lane];
    float ax = v.x, ay = v.y, az = v.z, aw = v.w;
    int b = rs[node], e = rs[node + 1];
    for (int i = b; i < e; ++i) {
        int s = eb[i];
        float4 u = xv[(size_t)s * 16 + lane];
        ax += u.x; ay += u.y; az += u.z; aw += u.w;
    }
    float dv = dinv[node];
    const float4* bv = (const float4*)bias;
    float4 bb = bv[lane];
    float4 o;
    o.x = ax * dv + bb.x; o.y = ay * dv + bb.y; o.z = az * dv + bb.z; o.w = aw * dv + bb.w;
    ((float4*)out)[(size_t)node * 16 + lane] = o;
}

// ---------- batch-norm ----------
__global__ void k_stats(const float* __restrict__ h, float* __restrict__ gsum,
                        float* __restrict__ gsq, int n) {
    int c = threadIdx.x & 127;
    int half = threadIdx.x >> 7;
    float s = 0.f, s2 = 0.f;
    for (int r = blockIdx.x * 2 + half; r < n; r += gridDim.x * 2) {
        float v = h[(size_t)r * 128 + c];
        s += v; s2 += v * v;
    }
    __shared__ float ls[256], ls2[256];
    ls[threadIdx.x] = s; ls2[threadIdx.x] = s2;
    __syncthreads();
    if (threadIdx.x < 128) {
        atomicAdd(&gsum[c], ls[threadIdx.x] + ls[threadIdx.x + 128]);
        atomicAdd(&gsq[c],  ls2[threadIdx.x] + ls2[threadIdx.x + 128]);
    }
}

__global__ void k_finalize(const float* __restrict__ gsum, const float* __restrict__ gsq,
                           const float* __restrict__ gamma, const float* __restrict__ beta,
                           float* __restrict__ scale, float* __restrict__ shift, float inv_n) {
    int c = threadIdx.x;  // 128 threads
    float m = gsum[c] * inv_n;
    float v = gsq[c] * inv_n - m * m;
    float sc = gamma[c] * rsqrtf(v + BN_EPS);
    scale[c] = sc;
    shift[c] = beta[c] - m * sc;
}

__global__ void k_bnrelu_res(float* __restrict__ out, const float* __restrict__ agg,
                             const float* __restrict__ scale, const float* __restrict__ shift,
                             const float* __restrict__ res, int total) {
    int gid = blockIdx.x * 256 + threadIdx.x;
    if (gid >= total) return;
    int c = gid & 127;
    float v = fmaf(agg[gid], scale[c], shift[c]);
    v = v > 0.f ? v : 0.f;
    out[gid] = v + res[gid];
}

extern "C" void kernel_launch(void* const* d_in, const int* in_sizes, int n_in,
                              void* d_out, int out_size, void* d_ws, size_t ws_size,
                              hipStream_t stream) {
    const float* x   = (const float*)d_in[0];
    const int*   ei  = (const int*)d_in[1];
    const float* W1  = (const float*)d_in[2];
    const float* W2  = (const float*)d_in[4];
    const float* W3  = (const float*)d_in[6];
    const float* b3  = (const float*)d_in[7];
    const float* g1  = (const float*)d_in[8];
    const float* be1 = (const float*)d_in[9];
    const float* g2  = (const float*)d_in[10];
    const float* be2 = (const float*)d_in[11];
    float* out = (float*)d_out;

    const int N = in_sizes[0] / 128;
    const int E = in_sizes[1] / 2;
    const int* src = ei;
    const int* dst = ei + E;

    char* p = (char*)d_ws;
    float* dinv  = (float*)p;            p += (size_t)N * 4;
    float* xs    = (float*)p;            p += (size_t)N * 128 * 4;
    float* agg   = (float*)p;            p += (size_t)N * 128 * 4;
    float* h1    = (float*)p;            p += (size_t)N * 128 * 4;
    float* gsum  = (float*)p;            p += 128 * 4;
    float* gsq   = (float*)p;            p += 128 * 4;
    float* scale = (float*)p;            p += 128 * 4;
    float* shift = (float*)p;            p += 128 * 4;
    int*   cnt   = (int*)p;              p += (size_t)N * 4;
    int*   rs    = (int*)p;              p += (size_t)(N + 16) * 4;
    int*   cursor= (int*)p;              p += (size_t)N * 4;
    int*   eb    = (int*)p;              p += (size_t)E * 4;

    const int B = 256;
    const int gE  = (E + B - 1) / B;
    const int gN  = (N + B - 1) / B;
    const int gNF = (N * 128 + B - 1) / B;
    const int gT  = (N + 63) / 64;          // 64-row GEMM tiles
    const float inv_n = 1.0f / (float)N;

    // ---- CSR build + normalization ----
    hipMemsetAsync(cnt, 0, (size_t)N * 4, stream);
    k_cnt_deg<<<gE, B, 0, stream>>>(cnt, dst, E);
    k_scan<<<1, 256, 0, stream>>>(cnt, rs, N);
    k_dinv_from_cnt<<<gN, B, 0, stream>>>(dinv, cnt, N);
    hipMemcpyAsync(cursor, rs, (size_t)N * 4, hipMemcpyDeviceToDevice, stream);
    k_bucket<<<gE, B, 0, stream>>>(src, dst, cursor, eb, E);

    // ---- layer 1 ----
    k_gemm128_t<<<gT, B, 0, stream>>>(x, W1, xs, dinv, N);
    k_gather128<<<(N + 7) / 8, B, 0, stream>>>(agg, xs, rs, eb, dinv, N);
    hipMemsetAsync(gsum, 0, 2 * 128 * 4, stream);
    k_stats<<<512, B, 0, stream>>>(agg, gsum, gsq, N);
    k_finalize<<<1, 128, 0, stream>>>(gsum, gsq, g1, be1, scale, shift, inv_n);
    k_bnrelu_res<<<gNF, B, 0, stream>>>(h1, agg, scale, shift, x, N * 128);

    // ---- layer 2 ----
    k_gemm128_t<<<gT, B, 0, stream>>>(h1, W2, xs, dinv, N);
    k_gather128<<<(N + 7) / 8, B, 0, stream>>>(agg, xs, rs, eb, dinv, N);
    hipMemsetAsync(gsum, 0, 2 * 128 * 4, stream);
    k_stats<<<512, B, 0, stream>>>(agg, gsum, gsq, N);
    k_finalize<<<1, 128, 0, stream>>>(gsum, gsq, g2, be2, scale, shift, inv_n);
    k_bnrelu_res<<<gNF, B, 0, stream>>>(agg, agg, scale, shift, h1, N * 128);

    // ---- output layer ----
    k_gemm64_t<<<gT, B, 0, stream>>>(agg, W3, xs, dinv, N);
    k_gather64_bias<<<(N + 15) / 16, B, 0, stream>>>(out, xs, rs, eb, dinv, b3, N);
}

// Round 4
// 548.474 us; speedup vs baseline: 2.8378x; 1.1255x over previous
//
#include <hip/hip_runtime.h>

// GCN encoder: 3x GCNConv (sym-norm, self-loops) + 2x BatchNorm(train)+ReLU+residual.
// N=50000, E=800000, IN=HID=128, OUT=64. fp32; edge_index int32.
//
// R2: CSR gather (no fp32 atomics), dinv folded into GEMM epilogue.
// R3: register-tiled GEMMs (64-row tile, per-thread 4x8 / 4x4, W in LDS).
// R4: single-block k_scan (86us, 0.04% occupancy) -> 3-pass hierarchical scan
//     (~8us); cursor initialization fused into scan pass 3 (drops the d2d copy).
// BN bias-cancel: b1/b2 vanish inside BatchNorm; only b3 applied.

#define BN_EPS 1e-5f

// ---------- CSR build ----------
__global__ void k_cnt_deg(int* __restrict__ cnt, const int* __restrict__ dst, int e) {
    int i = blockIdx.x * 256 + threadIdx.x;
    if (i < e) atomicAdd(&cnt[dst[i]], 1);
}

// pass 1: per-block exclusive scan of 256-element chunks; block sums out.
__global__ void k_scan1(const int* __restrict__ cnt, int* __restrict__ rs,
                        int* __restrict__ bsum, int n) {
    __shared__ int buf[256];
    const int t = threadIdx.x;
    const int i = blockIdx.x * 256 + t;
    const int v = (i < n) ? cnt[i] : 0;
    buf[t] = v;
    __syncthreads();
    for (int off = 1; off < 256; off <<= 1) {
        int add = (t >= off) ? buf[t - off] : 0;
        __syncthreads();
        buf[t] += add;
        __syncthreads();
    }
    if (i < n) rs[i] = buf[t] - v;           // exclusive
    if (t == 255) bsum[blockIdx.x] = buf[255];
}

// pass 2: single-block exclusive scan of bsum[0..nb) (nb<=256); grand total -> rs[n].
__global__ void k_scan2(int* __restrict__ bsum, int nb, int* __restrict__ rs, int n) {
    __shared__ int buf[256];
    const int t = threadIdx.x;
    const int v = (t < nb) ? bsum[t] : 0;
    buf[t] = v;
    __syncthreads();
    for (int off = 1; off < 256; off <<= 1) {
        int add = (t >= off) ? buf[t - off] : 0;
        __syncthreads();
        buf[t] += add;
        __syncthreads();
    }
    if (t < nb) bsum[t] = buf[t] - v;        // exclusive block offsets
    if (t == 255) rs[n] = buf[255];          // grand total (== E)
}

// pass 3: add block offsets; also materialize cursor = rs (bucket-fill cursors).
__global__ void k_scan3(int* __restrict__ rs, int* __restrict__ cursor,
                        const int* __restrict__ bsum, int n) {
    int i = blockIdx.x * 256 + threadIdx.x;
    if (i < n) {
        int v = rs[i] + bsum[blockIdx.x];
        rs[i] = v;
        cursor[i] = v;
    }
}

__global__ void k_dinv_from_cnt(float* __restrict__ dinv, const int* __restrict__ cnt, int n) {
    int i = blockIdx.x * 256 + threadIdx.x;
    if (i < n) dinv[i] = rsqrtf((float)(cnt[i] + 1));  // +1 self-loop
}

__global__ void k_bucket(const int* __restrict__ src, const int* __restrict__ dst,
                         int* __restrict__ cursor, int* __restrict__ eb, int e) {
    int i = blockIdx.x * 256 + threadIdx.x;
    if (i < e) {
        int d = dst[i];
        int p = atomicAdd(&cursor[d], 1);
        eb[p] = src[i];
    }
}

// ---------- register-tiled GEMMs ----------
__global__ __launch_bounds__(256) void k_gemm128_t(
        const float* __restrict__ A, const float* __restrict__ W,
        float* __restrict__ xs, const float* __restrict__ dinv, int n) {
    __shared__ float Wt[32][128];  // one 32-k chunk of W, 16 KB
    const int t  = threadIdx.x;
    const int cg = t & 15;
    const int rg = t >> 4;
    const int row0 = blockIdx.x * 64 + rg * 4;

    const float* a_r[4];
#pragma unroll
    for (int r = 0; r < 4; ++r) a_r[r] = A + (size_t)min(row0 + r, n - 1) * 128;

    float acc[4][8];
#pragma unroll
    for (int r = 0; r < 4; ++r)
#pragma unroll
        for (int c = 0; c < 8; ++c) acc[r][c] = 0.f;

    for (int kc = 0; kc < 4; ++kc) {
        const float4* wsrc = (const float4*)(W + (size_t)kc * 32 * 128);
        float4* wdst = (float4*)&Wt[0][0];
#pragma unroll
        for (int i = 0; i < 4; ++i) wdst[t + 256 * i] = wsrc[t + 256 * i];
        __syncthreads();

#pragma unroll
        for (int k4 = 0; k4 < 8; ++k4) {
            float4 a[4];
#pragma unroll
            for (int r = 0; r < 4; ++r)
                a[r] = *(const float4*)(a_r[r] + kc * 32 + k4 * 4);
#pragma unroll
            for (int j = 0; j < 4; ++j) {
                const int k = k4 * 4 + j;
                float4 w0 = *(const float4*)&Wt[k][cg * 4];
                float4 w1 = *(const float4*)&Wt[k][64 + cg * 4];
#pragma unroll
                for (int r = 0; r < 4; ++r) {
                    const float av = (&a[r].x)[j];
                    acc[r][0] = fmaf(av, w0.x, acc[r][0]);
                    acc[r][1] = fmaf(av, w0.y, acc[r][1]);
                    acc[r][2] = fmaf(av, w0.z, acc[r][2]);
                    acc[r][3] = fmaf(av, w0.w, acc[r][3]);
                    acc[r][4] = fmaf(av, w1.x, acc[r][4]);
                    acc[r][5] = fmaf(av, w1.y, acc[r][5]);
                    acc[r][6] = fmaf(av, w1.z, acc[r][6]);
                    acc[r][7] = fmaf(av, w1.w, acc[r][7]);
                }
            }
        }
        __syncthreads();
    }

#pragma unroll
    for (int r = 0; r < 4; ++r) {
        const int row = row0 + r;
        if (row < n) {
            const float dv = dinv[row];
            float4 o0 = { acc[r][0] * dv, acc[r][1] * dv, acc[r][2] * dv, acc[r][3] * dv };
            float4 o1 = { acc[r][4] * dv, acc[r][5] * dv, acc[r][6] * dv, acc[r][7] * dv };
            *(float4*)(xs + (size_t)row * 128 + cg * 4) = o0;
            *(float4*)(xs + (size_t)row * 128 + 64 + cg * 4) = o1;
        }
    }
}

__global__ __launch_bounds__(256) void k_gemm64_t(
        const float* __restrict__ A, const float* __restrict__ W,
        float* __restrict__ xs, const float* __restrict__ dinv, int n) {
    __shared__ float Wt[32][64];  // 8 KB chunk
    const int t  = threadIdx.x;
    const int cg = t & 15;
    const int rg = t >> 4;
    const int row0 = blockIdx.x * 64 + rg * 4;

    const float* a_r[4];
#pragma unroll
    for (int r = 0; r < 4; ++r) a_r[r] = A + (size_t)min(row0 + r, n - 1) * 128;

    float acc[4][4];
#pragma unroll
    for (int r = 0; r < 4; ++r)
#pragma unroll
        for (int c = 0; c < 4; ++c) acc[r][c] = 0.f;

    for (int kc = 0; kc < 4; ++kc) {
        const float4* wsrc = (const float4*)(W + (size_t)kc * 32 * 64);
        float4* wdst = (float4*)&Wt[0][0];
#pragma unroll
        for (int i = 0; i < 2; ++i) wdst[t + 256 * i] = wsrc[t + 256 * i];
        __syncthreads();

#pragma unroll
        for (int k4 = 0; k4 < 8; ++k4) {
            float4 a[4];
#pragma unroll
            for (int r = 0; r < 4; ++r)
                a[r] = *(const float4*)(a_r[r] + kc * 32 + k4 * 4);
#pragma unroll
            for (int j = 0; j < 4; ++j) {
                const int k = k4 * 4 + j;
                float4 w = *(const float4*)&Wt[k][cg * 4];
#pragma unroll
                for (int r = 0; r < 4; ++r) {
                    const float av = (&a[r].x)[j];
                    acc[r][0] = fmaf(av, w.x, acc[r][0]);
                    acc[r][1] = fmaf(av, w.y, acc[r][1]);
                    acc[r][2] = fmaf(av, w.z, acc[r][2]);
                    acc[r][3] = fmaf(av, w.w, acc[r][3]);
                }
            }
        }
        __syncthreads();
    }

#pragma unroll
    for (int r = 0; r < 4; ++r) {
        const int row = row0 + r;
        if (row < n) {
            const float dv = dinv[row];
            float4 o = { acc[r][0] * dv, acc[r][1] * dv, acc[r][2] * dv, acc[r][3] * dv };
            *(float4*)(xs + (size_t)row * 64 + cg * 4) = o;
        }
    }
}

// ---------- CSR gather aggregation ----------
__global__ void k_gather128(float* __restrict__ agg, const float* __restrict__ xs,
                            const int* __restrict__ rs, const int* __restrict__ eb,
                            const float* __restrict__ dinv, int n) {
    int node = blockIdx.x * 8 + (threadIdx.x >> 5);
    int lane = threadIdx.x & 31;
    if (node >= n) return;
    const float4* xv = (const float4*)xs;
    float4 v = xv[(size_t)node * 32 + lane];
    float ax = v.x, ay = v.y, az = v.z, aw = v.w;
    int b = rs[node], e = rs[node + 1];
    for (int i = b; i < e; ++i) {
        int s = eb[i];
        float4 u = xv[(size_t)s * 32 + lane];
        ax += u.x; ay += u.y; az += u.z; aw += u.w;
    }
    float dv = dinv[node];
    float4 o; o.x = ax * dv; o.y = ay * dv; o.z = az * dv; o.w = aw * dv;
    ((float4*)agg)[(size_t)node * 32 + lane] = o;
}

__global__ void k_gather64_bias(float* __restrict__ out, const float* __restrict__ xs,
                                const int* __restrict__ rs, const int* __restrict__ eb,
                                const float* __restrict__ dinv, const float* __restrict__ bias,
                                int n) {
    int node = blockIdx.x * 16 + (threadIdx.x >> 4);
    int lane = threadIdx.x & 15;
    if (node >= n) return;
    const float4* xv = (const float4*)xs;
    float4 v = xv[(size_t)node * 16 + lane];
    float ax = v.x, ay = v.y, az = v.z, aw = v.w;
    int b = rs[node], e = rs[node + 1];
    for (int i = b; i < e; ++i) {
        int s = eb[i];
        float4 u = xv[(size_t)s * 16 + lane];
        ax += u.x; ay += u.y; az += u.z; aw += u.w;
    }
    float dv = dinv[node];
    const float4* bv = (const float4*)bias;
    float4 bb = bv[lane];
    float4 o;
    o.x = ax * dv + bb.x; o.y = ay * dv + bb.y; o.z = az * dv + bb.z; o.w = aw * dv + bb.w;
    ((float4*)out)[(size_t)node * 16 + lane] = o;
}

// ---------- batch-norm ----------
__global__ void k_stats(const float* __restrict__ h, float* __restrict__ gsum,
                        float* __restrict__ gsq, int n) {
    int c = threadIdx.x & 127;
    int half = threadIdx.x >> 7;
    float s = 0.f, s2 = 0.f;
    for (int r = blockIdx.x * 2 + half; r < n; r += gridDim.x * 2) {
        float v = h[(size_t)r * 128 + c];
        s += v; s2 += v * v;
    }
    __shared__ float ls[256], ls2[256];
    ls[threadIdx.x] = s; ls2[threadIdx.x] = s2;
    __syncthreads();
    if (threadIdx.x < 128) {
        atomicAdd(&gsum[c], ls[threadIdx.x] + ls[threadIdx.x + 128]);
        atomicAdd(&gsq[c],  ls2[threadIdx.x] + ls2[threadIdx.x + 128]);
    }
}

__global__ void k_finalize(const float* __restrict__ gsum, const float* __restrict__ gsq,
                           const float* __restrict__ gamma, const float* __restrict__ beta,
                           float* __restrict__ scale, float* __restrict__ shift, float inv_n) {
    int c = threadIdx.x;  // 128 threads
    float m = gsum[c] * inv_n;
    float v = gsq[c] * inv_n - m * m;
    float sc = gamma[c] * rsqrtf(v + BN_EPS);
    scale[c] = sc;
    shift[c] = beta[c] - m * sc;
}

__global__ void k_bnrelu_res(float* __restrict__ out, const float* __restrict__ agg,
                             const float* __restrict__ scale, const float* __restrict__ shift,
                             const float* __restrict__ res, int total) {
    int gid = blockIdx.x * 256 + threadIdx.x;
    if (gid >= total) return;
    int c = gid & 127;
    float v = fmaf(agg[gid], scale[c], shift[c]);
    v = v > 0.f ? v : 0.f;
    out[gid] = v + res[gid];
}

extern "C" void kernel_launch(void* const* d_in, const int* in_sizes, int n_in,
                              void* d_out, int out_size, void* d_ws, size_t ws_size,
                              hipStream_t stream) {
    const float* x   = (const float*)d_in[0];
    const int*   ei  = (const int*)d_in[1];
    const float* W1  = (const float*)d_in[2];
    const float* W2  = (const float*)d_in[4];
    const float* W3  = (const float*)d_in[6];
    const float* b3  = (const float*)d_in[7];
    const float* g1  = (const float*)d_in[8];
    const float* be1 = (const float*)d_in[9];
    const float* g2  = (const float*)d_in[10];
    const float* be2 = (const float*)d_in[11];
    float* out = (float*)d_out;

    const int N = in_sizes[0] / 128;
    const int E = in_sizes[1] / 2;
    const int* src = ei;
    const int* dst = ei + E;

    char* p = (char*)d_ws;
    float* dinv  = (float*)p;            p += (size_t)N * 4;
    float* xs    = (float*)p;            p += (size_t)N * 128 * 4;
    float* agg   = (float*)p;            p += (size_t)N * 128 * 4;
    float* h1    = (float*)p;            p += (size_t)N * 128 * 4;
    float* gsum  = (float*)p;            p += 128 * 4;
    float* gsq   = (float*)p;            p += 128 * 4;
    float* scale = (float*)p;            p += 128 * 4;
    float* shift = (float*)p;            p += 128 * 4;
    int*   cnt   = (int*)p;              p += (size_t)N * 4;
    int*   rs    = (int*)p;              p += (size_t)(N + 16) * 4;
    int*   cursor= (int*)p;              p += (size_t)N * 4;
    int*   eb    = (int*)p;              p += (size_t)E * 4;
    int*   bsum  = (int*)p;              p += 256 * 4;

    const int B = 256;
    const int gE  = (E + B - 1) / B;
    const int gN  = (N + B - 1) / B;    // 196 blocks (scan passes reuse this)
    const int gNF = (N * 128 + B - 1) / B;
    const int gT  = (N + 63) / 64;
    const float inv_n = 1.0f / (float)N;

    // ---- CSR build + normalization ----
    hipMemsetAsync(cnt, 0, (size_t)N * 4, stream);
    k_cnt_deg<<<gE, B, 0, stream>>>(cnt, dst, E);
    k_scan1<<<gN, B, 0, stream>>>(cnt, rs, bsum, N);
    k_scan2<<<1, B, 0, stream>>>(bsum, gN, rs, N);
    k_scan3<<<gN, B, 0, stream>>>(rs, cursor, bsum, N);
    k_dinv_from_cnt<<<gN, B, 0, stream>>>(dinv, cnt, N);
    k_bucket<<<gE, B, 0, stream>>>(src, dst, cursor, eb, E);

    // ---- layer 1 ----
    k_gemm128_t<<<gT, B, 0, stream>>>(x, W1, xs, dinv, N);
    k_gather128<<<(N + 7) / 8, B, 0, stream>>>(agg, xs, rs, eb, dinv, N);
    hipMemsetAsync(gsum, 0, 2 * 128 * 4, stream);
    k_stats<<<512, B, 0, stream>>>(agg, gsum, gsq, N);
    k_finalize<<<1, 128, 0, stream>>>(gsum, gsq, g1, be1, scale, shift, inv_n);
    k_bnrelu_res<<<gNF, B, 0, stream>>>(h1, agg, scale, shift, x, N * 128);

    // ---- layer 2 ----
    k_gemm128_t<<<gT, B, 0, stream>>>(h1, W2, xs, dinv, N);
    k_gather128<<<(N + 7) / 8, B, 0, stream>>>(agg, xs, rs, eb, dinv, N);
    hipMemsetAsync(gsum, 0, 2 * 128 * 4, stream);
    k_stats<<<512, B, 0, stream>>>(agg, gsum, gsq, N);
    k_finalize<<<1, 128, 0, stream>>>(gsum, gsq, g2, be2, scale, shift, inv_n);
    k_bnrelu_res<<<gNF, B, 0, stream>>>(agg, agg, scale, shift, h1, N * 128);

    // ---- output layer ----
    k_gemm64_t<<<gT, B, 0, stream>>>(agg, W3, xs, dinv, N);
    k_gather64_bias<<<(N + 15) / 16, B, 0, stream>>>(out, xs, rs, eb, dinv, b3, N);
}

// Round 5
// 516.276 us; speedup vs baseline: 3.0148x; 1.0624x over previous
//
#include <hip/hip_runtime.h>

// GCN encoder: 3x GCNConv (sym-norm, self-loops) + 2x BatchNorm(train)+ReLU+residual.
// N=50000, E=800000, IN=HID=128, OUT=64. fp32 in/out; edge_index int32.
//
// R2: CSR gather (no fp32 atomics), dinv folded into GEMM epilogue.
// R3: register-tiled GEMMs (64-row tile, per-thread 4x8 / 4x4, W in LDS).
// R4: 3-pass hierarchical scan (was 86us single-block).
// R5: xs stored bf16 (gather traffic halved: 224MB->~112MB fetch/dispatch);
//     gather loop unrolled x2 (latency); BN+ReLU+residual fused into the
//     consumer GEMM's A-load (bnrelu kernels eliminated).
// BN bias-cancel: b1/b2 vanish inside BatchNorm; only b3 applied.

#define BN_EPS 1e-5f

__device__ __forceinline__ float bf2f(unsigned short u) {
    unsigned v = ((unsigned)u) << 16;
    return __builtin_bit_cast(float, v);
}
__device__ __forceinline__ unsigned short f2bf(float f) {
    unsigned u = __builtin_bit_cast(unsigned, f);
    u += 0x7fffu + ((u >> 16) & 1u);   // round-to-nearest-even
    return (unsigned short)(u >> 16);
}

// ---------- CSR build ----------
__global__ void k_cnt_deg(int* __restrict__ cnt, const int* __restrict__ dst, int e) {
    int i = blockIdx.x * 256 + threadIdx.x;
    if (i < e) atomicAdd(&cnt[dst[i]], 1);
}

__global__ void k_scan1(const int* __restrict__ cnt, int* __restrict__ rs,
                        int* __restrict__ bsum, int n) {
    __shared__ int buf[256];
    const int t = threadIdx.x;
    const int i = blockIdx.x * 256 + t;
    const int v = (i < n) ? cnt[i] : 0;
    buf[t] = v;
    __syncthreads();
    for (int off = 1; off < 256; off <<= 1) {
        int add = (t >= off) ? buf[t - off] : 0;
        __syncthreads();
        buf[t] += add;
        __syncthreads();
    }
    if (i < n) rs[i] = buf[t] - v;
    if (t == 255) bsum[blockIdx.x] = buf[255];
}

__global__ void k_scan2(int* __restrict__ bsum, int nb, int* __restrict__ rs, int n) {
    __shared__ int buf[256];
    const int t = threadIdx.x;
    const int v = (t < nb) ? bsum[t] : 0;
    buf[t] = v;
    __syncthreads();
    for (int off = 1; off < 256; off <<= 1) {
        int add = (t >= off) ? buf[t - off] : 0;
        __syncthreads();
        buf[t] += add;
        __syncthreads();
    }
    if (t < nb) bsum[t] = buf[t] - v;
    if (t == 255) rs[n] = buf[255];
}

__global__ void k_scan3(int* __restrict__ rs, int* __restrict__ cursor,
                        const int* __restrict__ bsum, int n) {
    int i = blockIdx.x * 256 + threadIdx.x;
    if (i < n) {
        int v = rs[i] + bsum[blockIdx.x];
        rs[i] = v;
        cursor[i] = v;
    }
}

__global__ void k_dinv_from_cnt(float* __restrict__ dinv, const int* __restrict__ cnt, int n) {
    int i = blockIdx.x * 256 + threadIdx.x;
    if (i < n) dinv[i] = rsqrtf((float)(cnt[i] + 1));
}

__global__ void k_bucket(const int* __restrict__ src, const int* __restrict__ dst,
                         int* __restrict__ cursor, int* __restrict__ eb, int e) {
    int i = blockIdx.x * 256 + threadIdx.x;
    if (i < e) {
        int d = dst[i];
        int p = atomicAdd(&cursor[d], 1);
        eb[p] = src[i];
    }
}

// ---------- GEMMs (register-tiled, bf16 output with dinv scaling) ----------
// Layer 1: C[n,128] = A[n,128] @ W, A read raw.
__global__ __launch_bounds__(256) void k_gemm128_bf(
        const float* __restrict__ A, const float* __restrict__ W,
        unsigned short* __restrict__ xs, const float* __restrict__ dinv, int n) {
    __shared__ float Wt[32][128];
    const int t  = threadIdx.x;
    const int cg = t & 15;
    const int rg = t >> 4;
    const int row0 = blockIdx.x * 64 + rg * 4;

    const float* a_r[4];
#pragma unroll
    for (int r = 0; r < 4; ++r) a_r[r] = A + (size_t)min(row0 + r, n - 1) * 128;

    float acc[4][8];
#pragma unroll
    for (int r = 0; r < 4; ++r)
#pragma unroll
        for (int c = 0; c < 8; ++c) acc[r][c] = 0.f;

    for (int kc = 0; kc < 4; ++kc) {
        const float4* wsrc = (const float4*)(W + (size_t)kc * 32 * 128);
        float4* wdst = (float4*)&Wt[0][0];
#pragma unroll
        for (int i = 0; i < 4; ++i) wdst[t + 256 * i] = wsrc[t + 256 * i];
        __syncthreads();

#pragma unroll
        for (int k4 = 0; k4 < 8; ++k4) {
            float4 a[4];
#pragma unroll
            for (int r = 0; r < 4; ++r)
                a[r] = *(const float4*)(a_r[r] + kc * 32 + k4 * 4);
#pragma unroll
            for (int j = 0; j < 4; ++j) {
                const int k = k4 * 4 + j;
                float4 w0 = *(const float4*)&Wt[k][cg * 4];
                float4 w1 = *(const float4*)&Wt[k][64 + cg * 4];
#pragma unroll
                for (int r = 0; r < 4; ++r) {
                    const float av = (&a[r].x)[j];
                    acc[r][0] = fmaf(av, w0.x, acc[r][0]);
                    acc[r][1] = fmaf(av, w0.y, acc[r][1]);
                    acc[r][2] = fmaf(av, w0.z, acc[r][2]);
                    acc[r][3] = fmaf(av, w0.w, acc[r][3]);
                    acc[r][4] = fmaf(av, w1.x, acc[r][4]);
                    acc[r][5] = fmaf(av, w1.y, acc[r][5]);
                    acc[r][6] = fmaf(av, w1.z, acc[r][6]);
                    acc[r][7] = fmaf(av, w1.w, acc[r][7]);
                }
            }
        }
        __syncthreads();
    }

#pragma unroll
    for (int r = 0; r < 4; ++r) {
        const int row = row0 + r;
        if (row < n) {
            const float dv = dinv[row];
            ushort4 o0 = { f2bf(acc[r][0] * dv), f2bf(acc[r][1] * dv),
                           f2bf(acc[r][2] * dv), f2bf(acc[r][3] * dv) };
            ushort4 o1 = { f2bf(acc[r][4] * dv), f2bf(acc[r][5] * dv),
                           f2bf(acc[r][6] * dv), f2bf(acc[r][7] * dv) };
            *(ushort4*)(xs + (size_t)row * 128 + cg * 4) = o0;
            *(ushort4*)(xs + (size_t)row * 128 + 64 + cg * 4) = o1;
        }
    }
}

// Layer 2: A = relu(bn(agg)) + res computed on the fly; side-writes h=A for later use.
__global__ __launch_bounds__(256) void k_gemm128_bn_bf(
        const float* __restrict__ agg, const float* __restrict__ res,
        const float* __restrict__ scale, const float* __restrict__ shift,
        float* __restrict__ h_out, const float* __restrict__ W,
        unsigned short* __restrict__ xs, const float* __restrict__ dinv, int n) {
    __shared__ float Wt[32][128];
    __shared__ float s_sc[128], s_sh[128];
    const int t  = threadIdx.x;
    const int cg = t & 15;
    const int rg = t >> 4;
    const int row0 = blockIdx.x * 64 + rg * 4;

    if (t < 128) s_sc[t] = scale[t];
    else         s_sh[t - 128] = shift[t - 128];

    int rowc[4];
#pragma unroll
    for (int r = 0; r < 4; ++r) rowc[r] = min(row0 + r, n - 1);

    float acc[4][8];
#pragma unroll
    for (int r = 0; r < 4; ++r)
#pragma unroll
        for (int c = 0; c < 8; ++c) acc[r][c] = 0.f;

    for (int kc = 0; kc < 4; ++kc) {
        const float4* wsrc = (const float4*)(W + (size_t)kc * 32 * 128);
        float4* wdst = (float4*)&Wt[0][0];
#pragma unroll
        for (int i = 0; i < 4; ++i) wdst[t + 256 * i] = wsrc[t + 256 * i];
        __syncthreads();

#pragma unroll
        for (int k4 = 0; k4 < 8; ++k4) {
            const int f = kc * 32 + k4 * 4;
            const float sc0 = s_sc[f], sc1 = s_sc[f + 1], sc2 = s_sc[f + 2], sc3 = s_sc[f + 3];
            const float sh0 = s_sh[f], sh1 = s_sh[f + 1], sh2 = s_sh[f + 2], sh3 = s_sh[f + 3];
            float4 a[4];
#pragma unroll
            for (int r = 0; r < 4; ++r) {
                float4 g  = *(const float4*)(agg + (size_t)rowc[r] * 128 + f);
                float4 rr = *(const float4*)(res + (size_t)rowc[r] * 128 + f);
                float4 h;
                h.x = fmaxf(fmaf(g.x, sc0, sh0), 0.f) + rr.x;
                h.y = fmaxf(fmaf(g.y, sc1, sh1), 0.f) + rr.y;
                h.z = fmaxf(fmaf(g.z, sc2, sh2), 0.f) + rr.z;
                h.w = fmaxf(fmaf(g.w, sc3, sh3), 0.f) + rr.w;
                a[r] = h;
                *(float4*)(h_out + (size_t)rowc[r] * 128 + f) = h;  // residual for next layer
            }
#pragma unroll
            for (int j = 0; j < 4; ++j) {
                const int k = k4 * 4 + j;
                float4 w0 = *(const float4*)&Wt[k][cg * 4];
                float4 w1 = *(const float4*)&Wt[k][64 + cg * 4];
#pragma unroll
                for (int r = 0; r < 4; ++r) {
                    const float av = (&a[r].x)[j];
                    acc[r][0] = fmaf(av, w0.x, acc[r][0]);
                    acc[r][1] = fmaf(av, w0.y, acc[r][1]);
                    acc[r][2] = fmaf(av, w0.z, acc[r][2]);
                    acc[r][3] = fmaf(av, w0.w, acc[r][3]);
                    acc[r][4] = fmaf(av, w1.x, acc[r][4]);
                    acc[r][5] = fmaf(av, w1.y, acc[r][5]);
                    acc[r][6] = fmaf(av, w1.z, acc[r][6]);
                    acc[r][7] = fmaf(av, w1.w, acc[r][7]);
                }
            }
        }
        __syncthreads();
    }

#pragma unroll
    for (int r = 0; r < 4; ++r) {
        const int row = row0 + r;
        if (row < n) {
            const float dv = dinv[row];
            ushort4 o0 = { f2bf(acc[r][0] * dv), f2bf(acc[r][1] * dv),
                           f2bf(acc[r][2] * dv), f2bf(acc[r][3] * dv) };
            ushort4 o1 = { f2bf(acc[r][4] * dv), f2bf(acc[r][5] * dv),
                           f2bf(acc[r][6] * dv), f2bf(acc[r][7] * dv) };
            *(ushort4*)(xs + (size_t)row * 128 + cg * 4) = o0;
            *(ushort4*)(xs + (size_t)row * 128 + 64 + cg * 4) = o1;
        }
    }
}

// Layer 3: C[n,64] = (relu(bn(agg))+res)[n,128] @ W[128,64]; no side-write.
__global__ __launch_bounds__(256) void k_gemm64_bn_bf(
        const float* __restrict__ agg, const float* __restrict__ res,
        const float* __restrict__ scale, const float* __restrict__ shift,
        const float* __restrict__ W,
        unsigned short* __restrict__ xs, const float* __restrict__ dinv, int n) {
    __shared__ float Wt[32][64];
    __shared__ float s_sc[128], s_sh[128];
    const int t  = threadIdx.x;
    const int cg = t & 15;
    const int rg = t >> 4;
    const int row0 = blockIdx.x * 64 + rg * 4;

    if (t < 128) s_sc[t] = scale[t];
    else         s_sh[t - 128] = shift[t - 128];

    int rowc[4];
#pragma unroll
    for (int r = 0; r < 4; ++r) rowc[r] = min(row0 + r, n - 1);

    float acc[4][4];
#pragma unroll
    for (int r = 0; r < 4; ++r)
#pragma unroll
        for (int c = 0; c < 4; ++c) acc[r][c] = 0.f;

    for (int kc = 0; kc < 4; ++kc) {
        const float4* wsrc = (const float4*)(W + (size_t)kc * 32 * 64);
        float4* wdst = (float4*)&Wt[0][0];
#pragma unroll
        for (int i = 0; i < 2; ++i) wdst[t + 256 * i] = wsrc[t + 256 * i];
        __syncthreads();

#pragma unroll
        for (int k4 = 0; k4 < 8; ++k4) {
            const int f = kc * 32 + k4 * 4;
            const float sc0 = s_sc[f], sc1 = s_sc[f + 1], sc2 = s_sc[f + 2], sc3 = s_sc[f + 3];
            const float sh0 = s_sh[f], sh1 = s_sh[f + 1], sh2 = s_sh[f + 2], sh3 = s_sh[f + 3];
            float4 a[4];
#pragma unroll
            for (int r = 0; r < 4; ++r) {
                float4 g  = *(const float4*)(agg + (size_t)rowc[r] * 128 + f);
                float4 rr = *(const float4*)(res + (size_t)rowc[r] * 128 + f);
                float4 h;
                h.x = fmaxf(fmaf(g.x, sc0, sh0), 0.f) + rr.x;
                h.y = fmaxf(fmaf(g.y, sc1, sh1), 0.f) + rr.y;
                h.z = fmaxf(fmaf(g.z, sc2, sh2), 0.f) + rr.z;
                h.w = fmaxf(fmaf(g.w, sc3, sh3), 0.f) + rr.w;
                a[r] = h;
            }
#pragma unroll
            for (int j = 0; j < 4; ++j) {
                const int k = k4 * 4 + j;
                float4 w = *(const float4*)&Wt[k][cg * 4];
#pragma unroll
                for (int r = 0; r < 4; ++r) {
                    const float av = (&a[r].x)[j];
                    acc[r][0] = fmaf(av, w.x, acc[r][0]);
                    acc[r][1] = fmaf(av, w.y, acc[r][1]);
                    acc[r][2] = fmaf(av, w.z, acc[r][2]);
                    acc[r][3] = fmaf(av, w.w, acc[r][3]);
                }
            }
        }
        __syncthreads();
    }

#pragma unroll
    for (int r = 0; r < 4; ++r) {
        const int row = row0 + r;
        if (row < n) {
            const float dv = dinv[row];
            ushort4 o = { f2bf(acc[r][0] * dv), f2bf(acc[r][1] * dv),
                          f2bf(acc[r][2] * dv), f2bf(acc[r][3] * dv) };
            *(ushort4*)(xs + (size_t)row * 64 + cg * 4) = o;
        }
    }
}

// ---------- CSR gather aggregation (bf16 rows, fp32 accumulate) ----------
__global__ void k_gather128(float* __restrict__ agg, const unsigned short* __restrict__ xs,
                            const int* __restrict__ rs, const int* __restrict__ eb,
                            const float* __restrict__ dinv, int n) {
    int node = blockIdx.x * 8 + (threadIdx.x >> 5);
    int lane = threadIdx.x & 31;
    if (node >= n) return;
    const ushort4* xv = (const ushort4*)xs;   // 32 x ushort4 per row
    ushort4 v = xv[(size_t)node * 32 + lane];
    float ax0 = bf2f(v.x), ay0 = bf2f(v.y), az0 = bf2f(v.z), aw0 = bf2f(v.w);
    float ax1 = 0.f, ay1 = 0.f, az1 = 0.f, aw1 = 0.f;
    int b = rs[node], e = rs[node + 1];
    int i = b;
    for (; i + 2 <= e; i += 2) {
        int s0 = eb[i], s1 = eb[i + 1];
        ushort4 u0 = xv[(size_t)s0 * 32 + lane];
        ushort4 u1 = xv[(size_t)s1 * 32 + lane];
        ax0 += bf2f(u0.x); ay0 += bf2f(u0.y); az0 += bf2f(u0.z); aw0 += bf2f(u0.w);
        ax1 += bf2f(u1.x); ay1 += bf2f(u1.y); az1 += bf2f(u1.z); aw1 += bf2f(u1.w);
    }
    if (i < e) {
        ushort4 u = xv[(size_t)eb[i] * 32 + lane];
        ax0 += bf2f(u.x); ay0 += bf2f(u.y); az0 += bf2f(u.z); aw0 += bf2f(u.w);
    }
    float dv = dinv[node];
    float4 o;
    o.x = (ax0 + ax1) * dv; o.y = (ay0 + ay1) * dv;
    o.z = (az0 + az1) * dv; o.w = (aw0 + aw1) * dv;
    ((float4*)agg)[(size_t)node * 32 + lane] = o;
}

__global__ void k_gather64_bias(float* __restrict__ out, const unsigned short* __restrict__ xs,
                                const int* __restrict__ rs, const int* __restrict__ eb,
                                const float* __restrict__ dinv, const float* __restrict__ bias,
                                int n) {
    int node = blockIdx.x * 16 + (threadIdx.x >> 4);
    int lane = threadIdx.x & 15;
    if (node >= n) return;
    const ushort4* xv = (const ushort4*)xs;   // 16 x ushort4 per row
    ushort4 v = xv[(size_t)node * 16 + lane];
    float ax0 = bf2f(v.x), ay0 = bf2f(v.y), az0 = bf2f(v.z), aw0 = bf2f(v.w);
    float ax1 = 0.f, ay1 = 0.f, az1 = 0.f, aw1 = 0.f;
    int b = rs[node], e = rs[node + 1];
    int i = b;
    for (; i + 2 <= e; i += 2) {
        int s0 = eb[i], s1 = eb[i + 1];
        ushort4 u0 = xv[(size_t)s0 * 16 + lane];
        ushort4 u1 = xv[(size_t)s1 * 16 + lane];
        ax0 += bf2f(u0.x); ay0 += bf2f(u0.y); az0 += bf2f(u0.z); aw0 += bf2f(u0.w);
        ax1 += bf2f(u1.x); ay1 += bf2f(u1.y); az1 += bf2f(u1.z); aw1 += bf2f(u1.w);
    }
    if (i < e) {
        ushort4 u = xv[(size_t)eb[i] * 16 + lane];
        ax0 += bf2f(u.x); ay0 += bf2f(u.y); az0 += bf2f(u.z); aw0 += bf2f(u.w);
    }
    float dv = dinv[node];
    const float4* bv = (const float4*)bias;
    float4 bb = bv[lane];
    float4 o;
    o.x = (ax0 + ax1) * dv + bb.x; o.y = (ay0 + ay1) * dv + bb.y;
    o.z = (az0 + az1) * dv + bb.z; o.w = (aw0 + aw1) * dv + bb.w;
    ((float4*)out)[(size_t)node * 16 + lane] = o;
}

// ---------- batch-norm stats ----------
__global__ void k_stats(const float* __restrict__ h, float* __restrict__ gsum,
                        float* __restrict__ gsq, int n) {
    int c = threadIdx.x & 127;
    int half = threadIdx.x >> 7;
    float s = 0.f, s2 = 0.f;
    for (int r = blockIdx.x * 2 + half; r < n; r += gridDim.x * 2) {
        float v = h[(size_t)r * 128 + c];
        s += v; s2 += v * v;
    }
    __shared__ float ls[256], ls2[256];
    ls[threadIdx.x] = s; ls2[threadIdx.x] = s2;
    __syncthreads();
    if (threadIdx.x < 128) {
        atomicAdd(&gsum[c], ls[threadIdx.x] + ls[threadIdx.x + 128]);
        atomicAdd(&gsq[c],  ls2[threadIdx.x] + ls2[threadIdx.x + 128]);
    }
}

__global__ void k_finalize(const float* __restrict__ gsum, const float* __restrict__ gsq,
                           const float* __restrict__ gamma, const float* __restrict__ beta,
                           float* __restrict__ scale, float* __restrict__ shift, float inv_n) {
    int c = threadIdx.x;  // 128 threads
    float m = gsum[c] * inv_n;
    float v = gsq[c] * inv_n - m * m;
    float sc = gamma[c] * rsqrtf(v + BN_EPS);
    scale[c] = sc;
    shift[c] = beta[c] - m * sc;
}

extern "C" void kernel_launch(void* const* d_in, const int* in_sizes, int n_in,
                              void* d_out, int out_size, void* d_ws, size_t ws_size,
                              hipStream_t stream) {
    const float* x   = (const float*)d_in[0];
    const int*   ei  = (const int*)d_in[1];
    const float* W1  = (const float*)d_in[2];
    const float* W2  = (const float*)d_in[4];
    const float* W3  = (const float*)d_in[6];
    const float* b3  = (const float*)d_in[7];
    const float* g1  = (const float*)d_in[8];
    const float* be1 = (const float*)d_in[9];
    const float* g2  = (const float*)d_in[10];
    const float* be2 = (const float*)d_in[11];
    float* out = (float*)d_out;

    const int N = in_sizes[0] / 128;
    const int E = in_sizes[1] / 2;
    const int* src = ei;
    const int* dst = ei + E;

    char* p = (char*)d_ws;
    float* dinv  = (float*)p;            p += (size_t)N * 4;
    unsigned short* xs = (unsigned short*)p; p += (size_t)N * 128 * 2;
    float* agg   = (float*)p;            p += (size_t)N * 128 * 4;
    float* h1    = (float*)p;            p += (size_t)N * 128 * 4;
    float* gsum  = (float*)p;            p += 128 * 4;
    float* gsq   = (float*)p;            p += 128 * 4;
    float* scale = (float*)p;            p += 128 * 4;
    float* shift = (float*)p;            p += 128 * 4;
    int*   cnt   = (int*)p;              p += (size_t)N * 4;
    int*   rs    = (int*)p;              p += (size_t)(N + 16) * 4;
    int*   cursor= (int*)p;              p += (size_t)N * 4;
    int*   eb    = (int*)p;              p += (size_t)E * 4;
    int*   bsum  = (int*)p;              p += 256 * 4;

    const int B = 256;
    const int gE  = (E + B - 1) / B;
    const int gN  = (N + B - 1) / B;
    const int gT  = (N + 63) / 64;
    const float inv_n = 1.0f / (float)N;

    // ---- CSR build + normalization ----
    hipMemsetAsync(cnt, 0, (size_t)N * 4, stream);
    k_cnt_deg<<<gE, B, 0, stream>>>(cnt, dst, E);
    k_scan1<<<gN, B, 0, stream>>>(cnt, rs, bsum, N);
    k_scan2<<<1, B, 0, stream>>>(bsum, gN, rs, N);
    k_scan3<<<gN, B, 0, stream>>>(rs, cursor, bsum, N);
    k_dinv_from_cnt<<<gN, B, 0, stream>>>(dinv, cnt, N);
    k_bucket<<<gE, B, 0, stream>>>(src, dst, cursor, eb, E);

    // ---- layer 1: xs1 = (x@W1)*dinv (bf16); agg1 = gather ----
    k_gemm128_bf<<<gT, B, 0, stream>>>(x, W1, xs, dinv, N);
    k_gather128<<<(N + 7) / 8, B, 0, stream>>>(agg, xs, rs, eb, dinv, N);
    hipMemsetAsync(gsum, 0, 2 * 128 * 4, stream);
    k_stats<<<512, B, 0, stream>>>(agg, gsum, gsq, N);
    k_finalize<<<1, 128, 0, stream>>>(gsum, gsq, g1, be1, scale, shift, inv_n);

    // ---- layer 2: h1 = relu(bn(agg1))+x fused into GEMM A-load; agg2 = gather ----
    k_gemm128_bn_bf<<<gT, B, 0, stream>>>(agg, x, scale, shift, h1, W2, xs, dinv, N);
    k_gather128<<<(N + 7) / 8, B, 0, stream>>>(agg, xs, rs, eb, dinv, N);
    hipMemsetAsync(gsum, 0, 2 * 128 * 4, stream);
    k_stats<<<512, B, 0, stream>>>(agg, gsum, gsq, N);
    k_finalize<<<1, 128, 0, stream>>>(gsum, gsq, g2, be2, scale, shift, inv_n);

    // ---- layer 3: h2 = relu(bn(agg2))+h1 fused; out = gather + b3 ----
    k_gemm64_bn_bf<<<gT, B, 0, stream>>>(agg, h1, scale, shift, W3, xs, dinv, N);
    k_gather64_bias<<<(N + 15) / 16, B, 0, stream>>>(out, xs, rs, eb, dinv, b3, N);
}

// Round 6
// 410.957 us; speedup vs baseline: 3.7874x; 1.2563x over previous
//
#include <hip/hip_runtime.h>

// GCN encoder: 3x GCNConv (sym-norm, self-loops) + 2x BatchNorm(train)+ReLU+residual.
// N=50000, E=800000, IN=HID=128, OUT=64. fp32 in/out; edge_index int32.
//
// R2: CSR gather (no fp32 atomics), dinv folded into GEMM epilogue.
// R3: register-tiled fp32 GEMMs.  R4: hierarchical scan.
// R5: xs bf16 (gather traffic halved), BN fused into GEMM A-load.
// R6: fp32 GEMM was latency-bound (VGPR=164, occ 8%, 19 TF). Replaced with
//     MFMA bf16 GEMM (v_mfma_f32_16x16x32_bf16): W packed to B-frag layout,
//     A converted to bf16 (dedicated bnrelu kernels emit fp32 residual + bf16
//     GEMM operand). fp32 accumulate, *dinv + bf16 store epilogue.
// BN bias-cancel: b1/b2 vanish inside BatchNorm; only b3 applied.

#define BN_EPS 1e-5f

typedef __attribute__((ext_vector_type(8))) short bf16x8;
typedef __attribute__((ext_vector_type(4))) float f32x4;

__device__ __forceinline__ float bf2f(unsigned short u) {
    unsigned v = ((unsigned)u) << 16;
    return __builtin_bit_cast(float, v);
}
__device__ __forceinline__ unsigned short f2bf(float f) {
    unsigned u = __builtin_bit_cast(unsigned, f);
    u += 0x7fffu + ((u >> 16) & 1u);   // round-to-nearest-even
    return (unsigned short)(u >> 16);
}

// ---------- CSR build ----------
__global__ void k_cnt_deg(int* __restrict__ cnt, const int* __restrict__ dst, int e) {
    int i = blockIdx.x * 256 + threadIdx.x;
    if (i < e) atomicAdd(&cnt[dst[i]], 1);
}

__global__ void k_scan1(const int* __restrict__ cnt, int* __restrict__ rs,
                        int* __restrict__ bsum, int n) {
    __shared__ int buf[256];
    const int t = threadIdx.x;
    const int i = blockIdx.x * 256 + t;
    const int v = (i < n) ? cnt[i] : 0;
    buf[t] = v;
    __syncthreads();
    for (int off = 1; off < 256; off <<= 1) {
        int add = (t >= off) ? buf[t - off] : 0;
        __syncthreads();
        buf[t] += add;
        __syncthreads();
    }
    if (i < n) rs[i] = buf[t] - v;
    if (t == 255) bsum[blockIdx.x] = buf[255];
}

__global__ void k_scan2(int* __restrict__ bsum, int nb, int* __restrict__ rs, int n) {
    __shared__ int buf[256];
    const int t = threadIdx.x;
    const int v = (t < nb) ? bsum[t] : 0;
    buf[t] = v;
    __syncthreads();
    for (int off = 1; off < 256; off <<= 1) {
        int add = (t >= off) ? buf[t - off] : 0;
        __syncthreads();
        buf[t] += add;
        __syncthreads();
    }
    if (t < nb) bsum[t] = buf[t] - v;
    if (t == 255) rs[n] = buf[255];
}

__global__ void k_scan3(int* __restrict__ rs, int* __restrict__ cursor,
                        const int* __restrict__ bsum, int n) {
    int i = blockIdx.x * 256 + threadIdx.x;
    if (i < n) {
        int v = rs[i] + bsum[blockIdx.x];
        rs[i] = v;
        cursor[i] = v;
    }
}

__global__ void k_dinv_from_cnt(float* __restrict__ dinv, const int* __restrict__ cnt, int n) {
    int i = blockIdx.x * 256 + threadIdx.x;
    if (i < n) dinv[i] = rsqrtf((float)(cnt[i] + 1));
}

__global__ void k_bucket(const int* __restrict__ src, const int* __restrict__ dst,
                         int* __restrict__ cursor, int* __restrict__ eb, int e) {
    int i = blockIdx.x * 256 + threadIdx.x;
    if (i < e) {
        int d = dst[i];
        int p = atomicAdd(&cursor[d], 1);
        eb[p] = src[i];
    }
}

// ---------- weight packing: W[k][n] fp32 -> bf16 B-fragment layout ----------
// frag (kc, ct): 64 lanes x 8 bf16; lane covers n=ct*16+(lane&15), k=kc*32+(lane>>4)*8+j
__global__ void k_packW(const float* __restrict__ W, unsigned short* __restrict__ Wp, int ncol) {
    const int nct = ncol >> 4;
    int tid = blockIdx.x * 256 + threadIdx.x;
    if (tid >= 4 * nct * 64) return;
    int lane = tid & 63;
    int f = tid >> 6;
    int ct = f % nct;
    int kc = f / nct;
    int n = ct * 16 + (lane & 15);
    int k0 = kc * 32 + (lane >> 4) * 8;
    ushort4 lo, hi;
    lo.x = f2bf(W[(size_t)(k0 + 0) * ncol + n]);
    lo.y = f2bf(W[(size_t)(k0 + 1) * ncol + n]);
    lo.z = f2bf(W[(size_t)(k0 + 2) * ncol + n]);
    lo.w = f2bf(W[(size_t)(k0 + 3) * ncol + n]);
    hi.x = f2bf(W[(size_t)(k0 + 4) * ncol + n]);
    hi.y = f2bf(W[(size_t)(k0 + 5) * ncol + n]);
    hi.z = f2bf(W[(size_t)(k0 + 6) * ncol + n]);
    hi.w = f2bf(W[(size_t)(k0 + 7) * ncol + n]);
    *(ushort4*)(Wp + (size_t)tid * 8)     = lo;
    *(ushort4*)(Wp + (size_t)tid * 8 + 4) = hi;
}

// fp32 -> bf16 bulk convert (float4 per thread)
__global__ void k_f2bf_vec(const float* __restrict__ in, unsigned short* __restrict__ ob, int total4) {
    int i = blockIdx.x * 256 + threadIdx.x;
    if (i < total4) {
        float4 v = ((const float4*)in)[i];
        ushort4 o = { f2bf(v.x), f2bf(v.y), f2bf(v.z), f2bf(v.w) };
        ((ushort4*)ob)[i] = o;
    }
}

// ---------- MFMA GEMMs ----------
// xs[n,128](bf16) = (Ab[n,128](bf16) @ W) * dinv[row].  Block: 64 rows, 4 waves x 16 rows.
__global__ __launch_bounds__(256) void k_gemm_mfma128(
        const unsigned short* __restrict__ Ab, const unsigned short* __restrict__ Wp,
        unsigned short* __restrict__ xs, const float* __restrict__ dinv, int n) {
    __shared__ __align__(16) unsigned short Wl[16384];  // 4 kc x 8 ct x 64 lanes x 8
    const int t = threadIdx.x;
    {
        const ushort4* s = (const ushort4*)Wp;
        ushort4* d = (ushort4*)Wl;
#pragma unroll
        for (int i = 0; i < 16; ++i) d[t + 256 * i] = s[t + 256 * i];
    }
    __syncthreads();
    const int lane = t & 63, wave = t >> 6;
    const int quad = lane >> 4, l15 = lane & 15;
    const int m0 = blockIdx.x * 64 + wave * 16;
    const int arow = min(m0 + l15, n - 1);

    f32x4 acc[8];
#pragma unroll
    for (int ct = 0; ct < 8; ++ct) acc[ct] = (f32x4){0.f, 0.f, 0.f, 0.f};

#pragma unroll
    for (int kc = 0; kc < 4; ++kc) {
        bf16x8 a = *(const bf16x8*)(Ab + (size_t)arow * 128 + kc * 32 + quad * 8);
#pragma unroll
        for (int ct = 0; ct < 8; ++ct) {
            bf16x8 b = *(const bf16x8*)(Wl + ((kc * 8 + ct) * 64 + lane) * 8);
            acc[ct] = __builtin_amdgcn_mfma_f32_16x16x32_bf16(a, b, acc[ct], 0, 0, 0);
        }
    }

    int rowv[4]; float dvv[4];
#pragma unroll
    for (int r = 0; r < 4; ++r) {
        rowv[r] = m0 + quad * 4 + r;
        dvv[r] = dinv[min(rowv[r], n - 1)];
    }
#pragma unroll
    for (int ct = 0; ct < 8; ++ct)
#pragma unroll
        for (int r = 0; r < 4; ++r)
            if (rowv[r] < n)
                xs[(size_t)rowv[r] * 128 + ct * 16 + l15] = f2bf(acc[ct][r] * dvv[r]);
}

// xs[n,64](bf16) = (Ab[n,128](bf16) @ W[128,64]) * dinv[row].
__global__ __launch_bounds__(256) void k_gemm_mfma64(
        const unsigned short* __restrict__ Ab, const unsigned short* __restrict__ Wp,
        unsigned short* __restrict__ xs, const float* __restrict__ dinv, int n) {
    __shared__ __align__(16) unsigned short Wl[8192];  // 4 kc x 4 ct x 64 x 8
    const int t = threadIdx.x;
    {
        const ushort4* s = (const ushort4*)Wp;
        ushort4* d = (ushort4*)Wl;
#pragma unroll
        for (int i = 0; i < 8; ++i) d[t + 256 * i] = s[t + 256 * i];
    }
    __syncthreads();
    const int lane = t & 63, wave = t >> 6;
    const int quad = lane >> 4, l15 = lane & 15;
    const int m0 = blockIdx.x * 64 + wave * 16;
    const int arow = min(m0 + l15, n - 1);

    f32x4 acc[4];
#pragma unroll
    for (int ct = 0; ct < 4; ++ct) acc[ct] = (f32x4){0.f, 0.f, 0.f, 0.f};

#pragma unroll
    for (int kc = 0; kc < 4; ++kc) {
        bf16x8 a = *(const bf16x8*)(Ab + (size_t)arow * 128 + kc * 32 + quad * 8);
#pragma unroll
        for (int ct = 0; ct < 4; ++ct) {
            bf16x8 b = *(const bf16x8*)(Wl + ((kc * 4 + ct) * 64 + lane) * 8);
            acc[ct] = __builtin_amdgcn_mfma_f32_16x16x32_bf16(a, b, acc[ct], 0, 0, 0);
        }
    }

    int rowv[4]; float dvv[4];
#pragma unroll
    for (int r = 0; r < 4; ++r) {
        rowv[r] = m0 + quad * 4 + r;
        dvv[r] = dinv[min(rowv[r], n - 1)];
    }
#pragma unroll
    for (int ct = 0; ct < 4; ++ct)
#pragma unroll
        for (int r = 0; r < 4; ++r)
            if (rowv[r] < n)
                xs[(size_t)rowv[r] * 64 + ct * 16 + l15] = f2bf(acc[ct][r] * dvv[r]);
}

// ---------- CSR gather aggregation (bf16 rows, fp32 accumulate) ----------
__global__ void k_gather128(float* __restrict__ agg, const unsigned short* __restrict__ xs,
                            const int* __restrict__ rs, const int* __restrict__ eb,
                            const float* __restrict__ dinv, int n) {
    int node = blockIdx.x * 8 + (threadIdx.x >> 5);
    int lane = threadIdx.x & 31;
    if (node >= n) return;
    const ushort4* xv = (const ushort4*)xs;
    ushort4 v = xv[(size_t)node * 32 + lane];
    float ax0 = bf2f(v.x), ay0 = bf2f(v.y), az0 = bf2f(v.z), aw0 = bf2f(v.w);
    float ax1 = 0.f, ay1 = 0.f, az1 = 0.f, aw1 = 0.f;
    int b = rs[node], e = rs[node + 1];
    int i = b;
    for (; i + 2 <= e; i += 2) {
        int s0 = eb[i], s1 = eb[i + 1];
        ushort4 u0 = xv[(size_t)s0 * 32 + lane];
        ushort4 u1 = xv[(size_t)s1 * 32 + lane];
        ax0 += bf2f(u0.x); ay0 += bf2f(u0.y); az0 += bf2f(u0.z); aw0 += bf2f(u0.w);
        ax1 += bf2f(u1.x); ay1 += bf2f(u1.y); az1 += bf2f(u1.z); aw1 += bf2f(u1.w);
    }
    if (i < e) {
        ushort4 u = xv[(size_t)eb[i] * 32 + lane];
        ax0 += bf2f(u.x); ay0 += bf2f(u.y); az0 += bf2f(u.z); aw0 += bf2f(u.w);
    }
    float dv = dinv[node];
    float4 o;
    o.x = (ax0 + ax1) * dv; o.y = (ay0 + ay1) * dv;
    o.z = (az0 + az1) * dv; o.w = (aw0 + aw1) * dv;
    ((float4*)agg)[(size_t)node * 32 + lane] = o;
}

__global__ void k_gather64_bias(float* __restrict__ out, const unsigned short* __restrict__ xs,
                                const int* __restrict__ rs, const int* __restrict__ eb,
                                const float* __restrict__ dinv, const float* __restrict__ bias,
                                int n) {
    int node = blockIdx.x * 16 + (threadIdx.x >> 4);
    int lane = threadIdx.x & 15;
    if (node >= n) return;
    const ushort4* xv = (const ushort4*)xs;
    ushort4 v = xv[(size_t)node * 16 + lane];
    float ax0 = bf2f(v.x), ay0 = bf2f(v.y), az0 = bf2f(v.z), aw0 = bf2f(v.w);
    float ax1 = 0.f, ay1 = 0.f, az1 = 0.f, aw1 = 0.f;
    int b = rs[node], e = rs[node + 1];
    int i = b;
    for (; i + 2 <= e; i += 2) {
        int s0 = eb[i], s1 = eb[i + 1];
        ushort4 u0 = xv[(size_t)s0 * 16 + lane];
        ushort4 u1 = xv[(size_t)s1 * 16 + lane];
        ax0 += bf2f(u0.x); ay0 += bf2f(u0.y); az0 += bf2f(u0.z); aw0 += bf2f(u0.w);
        ax1 += bf2f(u1.x); ay1 += bf2f(u1.y); az1 += bf2f(u1.z); aw1 += bf2f(u1.w);
    }
    if (i < e) {
        ushort4 u = xv[(size_t)eb[i] * 16 + lane];
        ax0 += bf2f(u.x); ay0 += bf2f(u.y); az0 += bf2f(u.z); aw0 += bf2f(u.w);
    }
    float dv = dinv[node];
    const float4* bv = (const float4*)bias;
    float4 bb = bv[lane];
    float4 o;
    o.x = (ax0 + ax1) * dv + bb.x; o.y = (ay0 + ay1) * dv + bb.y;
    o.z = (az0 + az1) * dv + bb.z; o.w = (aw0 + aw1) * dv + bb.w;
    ((float4*)out)[(size_t)node * 16 + lane] = o;
}

// ---------- batch-norm ----------
__global__ void k_stats(const float* __restrict__ h, float* __restrict__ gsum,
                        float* __restrict__ gsq, int n) {
    int c = threadIdx.x & 127;
    int half = threadIdx.x >> 7;
    float s = 0.f, s2 = 0.f;
    for (int r = blockIdx.x * 2 + half; r < n; r += gridDim.x * 2) {
        float v = h[(size_t)r * 128 + c];
        s += v; s2 += v * v;
    }
    __shared__ float ls[256], ls2[256];
    ls[threadIdx.x] = s; ls2[threadIdx.x] = s2;
    __syncthreads();
    if (threadIdx.x < 128) {
        atomicAdd(&gsum[c], ls[threadIdx.x] + ls[threadIdx.x + 128]);
        atomicAdd(&gsq[c],  ls2[threadIdx.x] + ls2[threadIdx.x + 128]);
    }
}

__global__ void k_finalize(const float* __restrict__ gsum, const float* __restrict__ gsq,
                           const float* __restrict__ gamma, const float* __restrict__ beta,
                           float* __restrict__ scale, float* __restrict__ shift, float inv_n) {
    int c = threadIdx.x;  // 128 threads
    float m = gsum[c] * inv_n;
    float v = gsq[c] * inv_n - m * m;
    float sc = gamma[c] * rsqrtf(v + BN_EPS);
    scale[c] = sc;
    shift[c] = beta[c] - m * sc;
}

// h = relu(bn(agg)) + res; writes fp32 h (next residual) AND bf16 hb (GEMM operand).
__global__ void k_bnrelu_dual(float* __restrict__ h, unsigned short* __restrict__ hb,
                              const float* __restrict__ agg, const float* __restrict__ res,
                              const float* __restrict__ scale, const float* __restrict__ shift,
                              int total4) {
    int i = blockIdx.x * 256 + threadIdx.x;
    if (i >= total4) return;
    int c = (i * 4) & 127;
    float4 g  = ((const float4*)agg)[i];
    float4 rr = ((const float4*)res)[i];
    float4 sc = *(const float4*)(scale + c);
    float4 sh = *(const float4*)(shift + c);
    float4 o;
    o.x = fmaxf(fmaf(g.x, sc.x, sh.x), 0.f) + rr.x;
    o.y = fmaxf(fmaf(g.y, sc.y, sh.y), 0.f) + rr.y;
    o.z = fmaxf(fmaf(g.z, sc.z, sh.z), 0.f) + rr.z;
    o.w = fmaxf(fmaf(g.w, sc.w, sh.w), 0.f) + rr.w;
    ((float4*)h)[i] = o;
    ushort4 ob = { f2bf(o.x), f2bf(o.y), f2bf(o.z), f2bf(o.w) };
    ((ushort4*)hb)[i] = ob;
}

// bf16-only variant (last activation: no further residual consumer).
__global__ void k_bnrelu_bf(unsigned short* __restrict__ hb,
                            const float* __restrict__ agg, const float* __restrict__ res,
                            const float* __restrict__ scale, const float* __restrict__ shift,
                            int total4) {
    int i = blockIdx.x * 256 + threadIdx.x;
    if (i >= total4) return;
    int c = (i * 4) & 127;
    float4 g  = ((const float4*)agg)[i];
    float4 rr = ((const float4*)res)[i];
    float4 sc = *(const float4*)(scale + c);
    float4 sh = *(const float4*)(shift + c);
    ushort4 ob;
    ob.x = f2bf(fmaxf(fmaf(g.x, sc.x, sh.x), 0.f) + rr.x);
    ob.y = f2bf(fmaxf(fmaf(g.y, sc.y, sh.y), 0.f) + rr.y);
    ob.z = f2bf(fmaxf(fmaf(g.z, sc.z, sh.z), 0.f) + rr.z);
    ob.w = f2bf(fmaxf(fmaf(g.w, sc.w, sh.w), 0.f) + rr.w);
    ((ushort4*)hb)[i] = ob;
}

extern "C" void kernel_launch(void* const* d_in, const int* in_sizes, int n_in,
                              void* d_out, int out_size, void* d_ws, size_t ws_size,
                              hipStream_t stream) {
    const float* x   = (const float*)d_in[0];
    const int*   ei  = (const int*)d_in[1];
    const float* W1  = (const float*)d_in[2];
    const float* W2  = (const float*)d_in[4];
    const float* W3  = (const float*)d_in[6];
    const float* b3  = (const float*)d_in[7];
    const float* g1  = (const float*)d_in[8];
    const float* be1 = (const float*)d_in[9];
    const float* g2  = (const float*)d_in[10];
    const float* be2 = (const float*)d_in[11];
    float* out = (float*)d_out;

    const int N = in_sizes[0] / 128;
    const int E = in_sizes[1] / 2;
    const int* src = ei;
    const int* dst = ei + E;

    char* p = (char*)d_ws;
    float* dinv  = (float*)p;               p += (size_t)N * 4;
    unsigned short* xb = (unsigned short*)p; p += (size_t)N * 128 * 2;  // GEMM A operand (bf16)
    unsigned short* xs = (unsigned short*)p; p += (size_t)N * 128 * 2;  // GEMM output (bf16)
    float* agg   = (float*)p;               p += (size_t)N * 128 * 4;
    float* h1    = (float*)p;               p += (size_t)N * 128 * 4;
    float* gsum  = (float*)p;               p += 128 * 4;
    float* gsq   = (float*)p;               p += 128 * 4;
    float* scale = (float*)p;               p += 128 * 4;
    float* shift = (float*)p;               p += 128 * 4;
    unsigned short* Wp1 = (unsigned short*)p; p += 16384 * 2;
    unsigned short* Wp2 = (unsigned short*)p; p += 16384 * 2;
    unsigned short* Wp3 = (unsigned short*)p; p += 8192 * 2;
    int*   cnt   = (int*)p;                 p += (size_t)N * 4;
    int*   rs    = (int*)p;                 p += (size_t)(N + 16) * 4;
    int*   cursor= (int*)p;                 p += (size_t)N * 4;
    int*   eb    = (int*)p;                 p += (size_t)E * 4;
    int*   bsum  = (int*)p;                 p += 256 * 4;

    const int B = 256;
    const int gE  = (E + B - 1) / B;
    const int gN  = (N + B - 1) / B;
    const int gT  = (N + 63) / 64;
    const int g4  = (N * 128 / 4 + B - 1) / B;
    const float inv_n = 1.0f / (float)N;

    // ---- CSR build + normalization + weight packing ----
    hipMemsetAsync(cnt, 0, (size_t)N * 4, stream);
    k_cnt_deg<<<gE, B, 0, stream>>>(cnt, dst, E);
    k_scan1<<<gN, B, 0, stream>>>(cnt, rs, bsum, N);
    k_scan2<<<1, B, 0, stream>>>(bsum, gN, rs, N);
    k_scan3<<<gN, B, 0, stream>>>(rs, cursor, bsum, N);
    k_dinv_from_cnt<<<gN, B, 0, stream>>>(dinv, cnt, N);
    k_bucket<<<gE, B, 0, stream>>>(src, dst, cursor, eb, E);
    k_packW<<<8, B, 0, stream>>>(W1, Wp1, 128);
    k_packW<<<8, B, 0, stream>>>(W2, Wp2, 128);
    k_packW<<<4, B, 0, stream>>>(W3, Wp3, 64);

    // ---- layer 1: xb = bf16(x); xs = (xb@W1)*dinv; agg = gather ----
    k_f2bf_vec<<<g4, B, 0, stream>>>(x, xb, N * 128 / 4);
    k_gemm_mfma128<<<gT, B, 0, stream>>>(xb, Wp1, xs, dinv, N);
    k_gather128<<<(N + 7) / 8, B, 0, stream>>>(agg, xs, rs, eb, dinv, N);
    hipMemsetAsync(gsum, 0, 2 * 128 * 4, stream);
    k_stats<<<512, B, 0, stream>>>(agg, gsum, gsq, N);
    k_finalize<<<1, 128, 0, stream>>>(gsum, gsq, g1, be1, scale, shift, inv_n);

    // ---- layer 2: h1 = relu(bn(agg))+x (fp32 + bf16); xs = (h1@W2)*dinv; agg = gather ----
    k_bnrelu_dual<<<g4, B, 0, stream>>>(h1, xb, agg, x, scale, shift, N * 128 / 4);
    k_gemm_mfma128<<<gT, B, 0, stream>>>(xb, Wp2, xs, dinv, N);
    k_gather128<<<(N + 7) / 8, B, 0, stream>>>(agg, xs, rs, eb, dinv, N);
    hipMemsetAsync(gsum, 0, 2 * 128 * 4, stream);
    k_stats<<<512, B, 0, stream>>>(agg, gsum, gsq, N);
    k_finalize<<<1, 128, 0, stream>>>(gsum, gsq, g2, be2, scale, shift, inv_n);

    // ---- layer 3: h2 = relu(bn(agg))+h1 (bf16 only); xs = (h2@W3)*dinv; out = gather+b3 ----
    k_bnrelu_bf<<<g4, B, 0, stream>>>(xb, agg, h1, scale, shift, N * 128 / 4);
    k_gemm_mfma64<<<gT, B, 0, stream>>>(xb, Wp3, xs, dinv, N);
    k_gather64_bias<<<(N + 15) / 16, B, 0, stream>>>(out, xs, rs, eb, dinv, b3, N);
}

// Round 7
// 353.807 us; speedup vs baseline: 4.3991x; 1.1615x over previous
//
#include <hip/hip_runtime.h>

// GCN encoder: 3x GCNConv (sym-norm, self-loops) + 2x BatchNorm(train)+ReLU+residual.
// N=50000, E=800000, IN=HID=128, OUT=64. fp32 in/out; edge_index int32.
//
// R2: CSR gather (no fp32 atomics).  R3: register-tiled GEMMs.  R4: hier. scan.
// R5: xs bf16.  R6: MFMA bf16 GEMMs (v_mfma_f32_16x16x32_bf16).
// R7: CSR build rebuilt as 2-level counting sort (coarse dst>>8 partition with
//     LDS staging + per-(block,bucket) window atomics, then per-bucket fine
//     sort in L2). Old k_bucket did 800k random 4B stores -> 51MB writeback.
//     Layer-1 GEMM reads fp32 x directly (k_f2bf_vec pass deleted).
// BN bias-cancel: b1/b2 vanish inside BatchNorm; only b3 applied.
// NOTE: N must be < 65536 for the u16 packing in k_partition (N=50000 ok).

#define BN_EPS 1e-5f

typedef __attribute__((ext_vector_type(8))) short bf16x8;
typedef __attribute__((ext_vector_type(4))) float f32x4;

__device__ __forceinline__ float bf2f(unsigned short u) {
    unsigned v = ((unsigned)u) << 16;
    return __builtin_bit_cast(float, v);
}
__device__ __forceinline__ unsigned short f2bf(float f) {
    unsigned u = __builtin_bit_cast(unsigned, f);
    u += 0x7fffu + ((u >> 16) & 1u);   // round-to-nearest-even
    return (unsigned short)(u >> 16);
}

// ---------- CSR build: 2-level counting sort ----------
// P1: coarse histogram of dst>>8 (256 bins; only ceil(N/256) used).
__global__ __launch_bounds__(256) void k_hist_coarse(const int* __restrict__ dst,
                                                     int* __restrict__ ccnt, int e) {
    __shared__ int hist[256];
    const int t = threadIdx.x;
    hist[t] = 0;
    __syncthreads();
    const int base = blockIdx.x * 4096;
    const int end = min(base + 4096, e);
    for (int idx = base + t; idx < end; idx += 256)
        atomicAdd(&hist[dst[idx] >> 8], 1);
    __syncthreads();
    if (hist[t] > 0) atomicAdd(&ccnt[t], hist[t]);
}

// P2: single-block scan of coarse counts -> bases + cursors; cbase[256]=total.
__global__ void k_scan_coarse(const int* __restrict__ ccnt, int* __restrict__ cbase,
                              int* __restrict__ ccur) {
    __shared__ int buf[256];
    const int t = threadIdx.x;
    const int v = ccnt[t];
    buf[t] = v;
    __syncthreads();
    for (int off = 1; off < 256; off <<= 1) {
        int add = (t >= off) ? buf[t - off] : 0;
        __syncthreads();
        buf[t] += add;
        __syncthreads();
    }
    const int ex = buf[t] - v;
    cbase[t] = ex;
    ccur[t] = ex;
    if (t == 255) cbase[256] = buf[255];
}

// P3: partition edges into coarse-bucket windows; pack (dst | src<<16) as u32.
__global__ __launch_bounds__(256) void k_partition(const int* __restrict__ src,
                                                   const int* __restrict__ dst,
                                                   int* __restrict__ ccur,
                                                   unsigned int* __restrict__ pairs, int e) {
    __shared__ unsigned short dl[4096], sl[4096];
    __shared__ int hist[256], basel[256], rnk[256];
    const int t = threadIdx.x;
    const int base = blockIdx.x * 4096;
    hist[t] = 0; rnk[t] = 0;
    __syncthreads();
#pragma unroll
    for (int i = 0; i < 16; ++i) {
        int idx = base + t + i * 256;
        if (idx < e) {
            int d = dst[idx];
            dl[t + i * 256] = (unsigned short)d;
            sl[t + i * 256] = (unsigned short)src[idx];
            atomicAdd(&hist[d >> 8], 1);
        }
    }
    __syncthreads();
    if (hist[t] > 0) basel[t] = atomicAdd(&ccur[t], hist[t]);
    __syncthreads();
#pragma unroll
    for (int i = 0; i < 16; ++i) {
        int idx = base + t + i * 256;
        if (idx < e) {
            int d = dl[t + i * 256];
            int bb = d >> 8;
            int r = atomicAdd(&rnk[bb], 1);
            pairs[basel[bb] + r] = (unsigned)d | ((unsigned)sl[t + i * 256] << 16);
        }
    }
}

// P4: per-coarse-bucket fine sort (256 dst values); emits rs, dinv, eb.
__global__ __launch_bounds__(256) void k_fine(const unsigned int* __restrict__ pairs,
                                              const int* __restrict__ cbase,
                                              int* __restrict__ rs, int* __restrict__ eb,
                                              float* __restrict__ dinv, int n, int e) {
    __shared__ int hist[256], fbase[256], cur[256], tmp[256];
    const int t = threadIdx.x;
    const int b = blockIdx.x;
    const int lo = cbase[b], hi = cbase[b + 1];
    hist[t] = 0; cur[t] = 0;
    __syncthreads();
    for (int pos = lo + t; pos < hi; pos += 256)
        atomicAdd(&hist[pairs[pos] & 255], 1);
    __syncthreads();
    const int v = hist[t];
    tmp[t] = v;
    __syncthreads();
    for (int off = 1; off < 256; off <<= 1) {
        int add = (t >= off) ? tmp[t - off] : 0;
        __syncthreads();
        tmp[t] += add;
        __syncthreads();
    }
    fbase[t] = tmp[t] - v;
    __syncthreads();
    const int node = b * 256 + t;
    if (node < n) {
        rs[node] = lo + fbase[t];
        dinv[node] = rsqrtf((float)(hist[t] + 1));  // +1 self-loop
    }
    if (b == 0 && t == 0) rs[n] = e;
    for (int pos = lo + t; pos < hi; pos += 256) {
        unsigned pr = pairs[pos];
        int local = pr & 255;
        int r = atomicAdd(&cur[local], 1);
        eb[lo + fbase[local] + r] = (int)(pr >> 16);
    }
}

// ---------- weight packing: W[k][n] fp32 -> bf16 B-fragment layout ----------
__global__ void k_packW(const float* __restrict__ W, unsigned short* __restrict__ Wp, int ncol) {
    const int nct = ncol >> 4;
    int tid = blockIdx.x * 256 + threadIdx.x;
    if (tid >= 4 * nct * 64) return;
    int lane = tid & 63;
    int f = tid >> 6;
    int ct = f % nct;
    int kc = f / nct;
    int n = ct * 16 + (lane & 15);
    int k0 = kc * 32 + (lane >> 4) * 8;
    ushort4 lo, hi;
    lo.x = f2bf(W[(size_t)(k0 + 0) * ncol + n]);
    lo.y = f2bf(W[(size_t)(k0 + 1) * ncol + n]);
    lo.z = f2bf(W[(size_t)(k0 + 2) * ncol + n]);
    lo.w = f2bf(W[(size_t)(k0 + 3) * ncol + n]);
    hi.x = f2bf(W[(size_t)(k0 + 4) * ncol + n]);
    hi.y = f2bf(W[(size_t)(k0 + 5) * ncol + n]);
    hi.z = f2bf(W[(size_t)(k0 + 6) * ncol + n]);
    hi.w = f2bf(W[(size_t)(k0 + 7) * ncol + n]);
    *(ushort4*)(Wp + (size_t)tid * 8)     = lo;
    *(ushort4*)(Wp + (size_t)tid * 8 + 4) = hi;
}

// ---------- MFMA GEMMs ----------
// xs[n,128](bf16) = (Ab[n,128](bf16) @ W) * dinv[row].  Block: 64 rows, 4 waves x 16 rows.
__global__ __launch_bounds__(256) void k_gemm_mfma128(
        const unsigned short* __restrict__ Ab, const unsigned short* __restrict__ Wp,
        unsigned short* __restrict__ xs, const float* __restrict__ dinv, int n) {
    __shared__ __align__(16) unsigned short Wl[16384];
    const int t = threadIdx.x;
    {
        const ushort4* s = (const ushort4*)Wp;
        ushort4* d = (ushort4*)Wl;
#pragma unroll
        for (int i = 0; i < 16; ++i) d[t + 256 * i] = s[t + 256 * i];
    }
    __syncthreads();
    const int lane = t & 63, wave = t >> 6;
    const int quad = lane >> 4, l15 = lane & 15;
    const int m0 = blockIdx.x * 64 + wave * 16;
    const int arow = min(m0 + l15, n - 1);

    f32x4 acc[8];
#pragma unroll
    for (int ct = 0; ct < 8; ++ct) acc[ct] = (f32x4){0.f, 0.f, 0.f, 0.f};

#pragma unroll
    for (int kc = 0; kc < 4; ++kc) {
        bf16x8 a = *(const bf16x8*)(Ab + (size_t)arow * 128 + kc * 32 + quad * 8);
#pragma unroll
        for (int ct = 0; ct < 8; ++ct) {
            bf16x8 b = *(const bf16x8*)(Wl + ((kc * 8 + ct) * 64 + lane) * 8);
            acc[ct] = __builtin_amdgcn_mfma_f32_16x16x32_bf16(a, b, acc[ct], 0, 0, 0);
        }
    }

    int rowv[4]; float dvv[4];
#pragma unroll
    for (int r = 0; r < 4; ++r) {
        rowv[r] = m0 + quad * 4 + r;
        dvv[r] = dinv[min(rowv[r], n - 1)];
    }
#pragma unroll
    for (int ct = 0; ct < 8; ++ct)
#pragma unroll
        for (int r = 0; r < 4; ++r)
            if (rowv[r] < n)
                xs[(size_t)rowv[r] * 128 + ct * 16 + l15] = f2bf(acc[ct][r] * dvv[r]);
}

// Same, but A read from fp32 (layer 1: avoids a separate convert pass).
__global__ __launch_bounds__(256) void k_gemm_mfma128_f32(
        const float* __restrict__ Af, const unsigned short* __restrict__ Wp,
        unsigned short* __restrict__ xs, const float* __restrict__ dinv, int n) {
    __shared__ __align__(16) unsigned short Wl[16384];
    const int t = threadIdx.x;
    {
        const ushort4* s = (const ushort4*)Wp;
        ushort4* d = (ushort4*)Wl;
#pragma unroll
        for (int i = 0; i < 16; ++i) d[t + 256 * i] = s[t + 256 * i];
    }
    __syncthreads();
    const int lane = t & 63, wave = t >> 6;
    const int quad = lane >> 4, l15 = lane & 15;
    const int m0 = blockIdx.x * 64 + wave * 16;
    const int arow = min(m0 + l15, n - 1);

    f32x4 acc[8];
#pragma unroll
    for (int ct = 0; ct < 8; ++ct) acc[ct] = (f32x4){0.f, 0.f, 0.f, 0.f};

#pragma unroll
    for (int kc = 0; kc < 4; ++kc) {
        float4 alo = *(const float4*)(Af + (size_t)arow * 128 + kc * 32 + quad * 8);
        float4 ahi = *(const float4*)(Af + (size_t)arow * 128 + kc * 32 + quad * 8 + 4);
        bf16x8 a;
        a[0] = (short)f2bf(alo.x); a[1] = (short)f2bf(alo.y);
        a[2] = (short)f2bf(alo.z); a[3] = (short)f2bf(alo.w);
        a[4] = (short)f2bf(ahi.x); a[5] = (short)f2bf(ahi.y);
        a[6] = (short)f2bf(ahi.z); a[7] = (short)f2bf(ahi.w);
#pragma unroll
        for (int ct = 0; ct < 8; ++ct) {
            bf16x8 b = *(const bf16x8*)(Wl + ((kc * 8 + ct) * 64 + lane) * 8);
            acc[ct] = __builtin_amdgcn_mfma_f32_16x16x32_bf16(a, b, acc[ct], 0, 0, 0);
        }
    }

    int rowv[4]; float dvv[4];
#pragma unroll
    for (int r = 0; r < 4; ++r) {
        rowv[r] = m0 + quad * 4 + r;
        dvv[r] = dinv[min(rowv[r], n - 1)];
    }
#pragma unroll
    for (int ct = 0; ct < 8; ++ct)
#pragma unroll
        for (int r = 0; r < 4; ++r)
            if (rowv[r] < n)
                xs[(size_t)rowv[r] * 128 + ct * 16 + l15] = f2bf(acc[ct][r] * dvv[r]);
}

// xs[n,64](bf16) = (Ab[n,128](bf16) @ W[128,64]) * dinv[row].
__global__ __launch_bounds__(256) void k_gemm_mfma64(
        const unsigned short* __restrict__ Ab, const unsigned short* __restrict__ Wp,
        unsigned short* __restrict__ xs, const float* __restrict__ dinv, int n) {
    __shared__ __align__(16) unsigned short Wl[8192];
    const int t = threadIdx.x;
    {
        const ushort4* s = (const ushort4*)Wp;
        ushort4* d = (ushort4*)Wl;
#pragma unroll
        for (int i = 0; i < 8; ++i) d[t + 256 * i] = s[t + 256 * i];
    }
    __syncthreads();
    const int lane = t & 63, wave = t >> 6;
    const int quad = lane >> 4, l15 = lane & 15;
    const int m0 = blockIdx.x * 64 + wave * 16;
    const int arow = min(m0 + l15, n - 1);

    f32x4 acc[4];
#pragma unroll
    for (int ct = 0; ct < 4; ++ct) acc[ct] = (f32x4){0.f, 0.f, 0.f, 0.f};

#pragma unroll
    for (int kc = 0; kc < 4; ++kc) {
        bf16x8 a = *(const bf16x8*)(Ab + (size_t)arow * 128 + kc * 32 + quad * 8);
#pragma unroll
        for (int ct = 0; ct < 4; ++ct) {
            bf16x8 b = *(const bf16x8*)(Wl + ((kc * 4 + ct) * 64 + lane) * 8);
            acc[ct] = __builtin_amdgcn_mfma_f32_16x16x32_bf16(a, b, acc[ct], 0, 0, 0);
        }
    }

    int rowv[4]; float dvv[4];
#pragma unroll
    for (int r = 0; r < 4; ++r) {
        rowv[r] = m0 + quad * 4 + r;
        dvv[r] = dinv[min(rowv[r], n - 1)];
    }
#pragma unroll
    for (int ct = 0; ct < 4; ++ct)
#pragma unroll
        for (int r = 0; r < 4; ++r)
            if (rowv[r] < n)
                xs[(size_t)rowv[r] * 64 + ct * 16 + l15] = f2bf(acc[ct][r] * dvv[r]);
}

// ---------- CSR gather aggregation (bf16 rows, fp32 accumulate) ----------
__global__ void k_gather128(float* __restrict__ agg, const unsigned short* __restrict__ xs,
                            const int* __restrict__ rs, const int* __restrict__ eb,
                            const float* __restrict__ dinv, int n) {
    int node = blockIdx.x * 8 + (threadIdx.x >> 5);
    int lane = threadIdx.x & 31;
    if (node >= n) return;
    const ushort4* xv = (const ushort4*)xs;
    ushort4 v = xv[(size_t)node * 32 + lane];
    float ax0 = bf2f(v.x), ay0 = bf2f(v.y), az0 = bf2f(v.z), aw0 = bf2f(v.w);
    float ax1 = 0.f, ay1 = 0.f, az1 = 0.f, aw1 = 0.f;
    int b = rs[node], e = rs[node + 1];
    int i = b;
    for (; i + 2 <= e; i += 2) {
        int s0 = eb[i], s1 = eb[i + 1];
        ushort4 u0 = xv[(size_t)s0 * 32 + lane];
        ushort4 u1 = xv[(size_t)s1 * 32 + lane];
        ax0 += bf2f(u0.x); ay0 += bf2f(u0.y); az0 += bf2f(u0.z); aw0 += bf2f(u0.w);
        ax1 += bf2f(u1.x); ay1 += bf2f(u1.y); az1 += bf2f(u1.z); aw1 += bf2f(u1.w);
    }
    if (i < e) {
        ushort4 u = xv[(size_t)eb[i] * 32 + lane];
        ax0 += bf2f(u.x); ay0 += bf2f(u.y); az0 += bf2f(u.z); aw0 += bf2f(u.w);
    }
    float dv = dinv[node];
    float4 o;
    o.x = (ax0 + ax1) * dv; o.y = (ay0 + ay1) * dv;
    o.z = (az0 + az1) * dv; o.w = (aw0 + aw1) * dv;
    ((float4*)agg)[(size_t)node * 32 + lane] = o;
}

__global__ void k_gather64_bias(float* __restrict__ out, const unsigned short* __restrict__ xs,
                                const int* __restrict__ rs, const int* __restrict__ eb,
                                const float* __restrict__ dinv, const float* __restrict__ bias,
                                int n) {
    int node = blockIdx.x * 16 + (threadIdx.x >> 4);
    int lane = threadIdx.x & 15;
    if (node >= n) return;
    const ushort4* xv = (const ushort4*)xs;
    ushort4 v = xv[(size_t)node * 16 + lane];
    float ax0 = bf2f(v.x), ay0 = bf2f(v.y), az0 = bf2f(v.z), aw0 = bf2f(v.w);
    float ax1 = 0.f, ay1 = 0.f, az1 = 0.f, aw1 = 0.f;
    int b = rs[node], e = rs[node + 1];
    int i = b;
    for (; i + 2 <= e; i += 2) {
        int s0 = eb[i], s1 = eb[i + 1];
        ushort4 u0 = xv[(size_t)s0 * 16 + lane];
        ushort4 u1 = xv[(size_t)s1 * 16 + lane];
        ax0 += bf2f(u0.x); ay0 += bf2f(u0.y); az0 += bf2f(u0.z); aw0 += bf2f(u0.w);
        ax1 += bf2f(u1.x); ay1 += bf2f(u1.y); az1 += bf2f(u1.z); aw1 += bf2f(u1.w);
    }
    if (i < e) {
        ushort4 u = xv[(size_t)eb[i] * 16 + lane];
        ax0 += bf2f(u.x); ay0 += bf2f(u.y); az0 += bf2f(u.z); aw0 += bf2f(u.w);
    }
    float dv = dinv[node];
    const float4* bv = (const float4*)bias;
    float4 bb = bv[lane];
    float4 o;
    o.x = (ax0 + ax1) * dv + bb.x; o.y = (ay0 + ay1) * dv + bb.y;
    o.z = (az0 + az1) * dv + bb.z; o.w = (aw0 + aw1) * dv + bb.w;
    ((float4*)out)[(size_t)node * 16 + lane] = o;
}

// ---------- batch-norm ----------
__global__ void k_stats(const float* __restrict__ h, float* __restrict__ gsum,
                        float* __restrict__ gsq, int n) {
    int c = threadIdx.x & 127;
    int half = threadIdx.x >> 7;
    float s = 0.f, s2 = 0.f;
    for (int r = blockIdx.x * 2 + half; r < n; r += gridDim.x * 2) {
        float v = h[(size_t)r * 128 + c];
        s += v; s2 += v * v;
    }
    __shared__ float ls[256], ls2[256];
    ls[threadIdx.x] = s; ls2[threadIdx.x] = s2;
    __syncthreads();
    if (threadIdx.x < 128) {
        atomicAdd(&gsum[c], ls[threadIdx.x] + ls[threadIdx.x + 128]);
        atomicAdd(&gsq[c],  ls2[threadIdx.x] + ls2[threadIdx.x + 128]);
    }
}

__global__ void k_finalize(const float* __restrict__ gsum, const float* __restrict__ gsq,
                           const float* __restrict__ gamma, const float* __restrict__ beta,
                           float* __restrict__ scale, float* __restrict__ shift, float inv_n) {
    int c = threadIdx.x;  // 128 threads
    float m = gsum[c] * inv_n;
    float v = gsq[c] * inv_n - m * m;
    float sc = gamma[c] * rsqrtf(v + BN_EPS);
    scale[c] = sc;
    shift[c] = beta[c] - m * sc;
}

// h = relu(bn(agg)) + res; writes fp32 h (next residual) AND bf16 hb (GEMM operand).
__global__ void k_bnrelu_dual(float* __restrict__ h, unsigned short* __restrict__ hb,
                              const float* __restrict__ agg, const float* __restrict__ res,
                              const float* __restrict__ scale, const float* __restrict__ shift,
                              int total4) {
    int i = blockIdx.x * 256 + threadIdx.x;
    if (i >= total4) return;
    int c = (i * 4) & 127;
    float4 g  = ((const float4*)agg)[i];
    float4 rr = ((const float4*)res)[i];
    float4 sc = *(const float4*)(scale + c);
    float4 sh = *(const float4*)(shift + c);
    float4 o;
    o.x = fmaxf(fmaf(g.x, sc.x, sh.x), 0.f) + rr.x;
    o.y = fmaxf(fmaf(g.y, sc.y, sh.y), 0.f) + rr.y;
    o.z = fmaxf(fmaf(g.z, sc.z, sh.z), 0.f) + rr.z;
    o.w = fmaxf(fmaf(g.w, sc.w, sh.w), 0.f) + rr.w;
    ((float4*)h)[i] = o;
    ushort4 ob = { f2bf(o.x), f2bf(o.y), f2bf(o.z), f2bf(o.w) };
    ((ushort4*)hb)[i] = ob;
}

// bf16-only variant (last activation: no further residual consumer).
__global__ void k_bnrelu_bf(unsigned short* __restrict__ hb,
                            const float* __restrict__ agg, const float* __restrict__ res,
                            const float* __restrict__ scale, const float* __restrict__ shift,
                            int total4) {
    int i = blockIdx.x * 256 + threadIdx.x;
    if (i >= total4) return;
    int c = (i * 4) & 127;
    float4 g  = ((const float4*)agg)[i];
    float4 rr = ((const float4*)res)[i];
    float4 sc = *(const float4*)(scale + c);
    float4 sh = *(const float4*)(shift + c);
    ushort4 ob;
    ob.x = f2bf(fmaxf(fmaf(g.x, sc.x, sh.x), 0.f) + rr.x);
    ob.y = f2bf(fmaxf(fmaf(g.y, sc.y, sh.y), 0.f) + rr.y);
    ob.z = f2bf(fmaxf(fmaf(g.z, sc.z, sh.z), 0.f) + rr.z);
    ob.w = f2bf(fmaxf(fmaf(g.w, sc.w, sh.w), 0.f) + rr.w);
    ((ushort4*)hb)[i] = ob;
}

extern "C" void kernel_launch(void* const* d_in, const int* in_sizes, int n_in,
                              void* d_out, int out_size, void* d_ws, size_t ws_size,
                              hipStream_t stream) {
    const float* x   = (const float*)d_in[0];
    const int*   ei  = (const int*)d_in[1];
    const float* W1  = (const float*)d_in[2];
    const float* W2  = (const float*)d_in[4];
    const float* W3  = (const float*)d_in[6];
    const float* b3  = (const float*)d_in[7];
    const float* g1  = (const float*)d_in[8];
    const float* be1 = (const float*)d_in[9];
    const float* g2  = (const float*)d_in[10];
    const float* be2 = (const float*)d_in[11];
    float* out = (float*)d_out;

    const int N = in_sizes[0] / 128;
    const int E = in_sizes[1] / 2;
    const int* src = ei;
    const int* dst = ei + E;

    char* p = (char*)d_ws;
    float* dinv  = (float*)p;               p += (size_t)N * 4;
    unsigned short* xb = (unsigned short*)p; p += (size_t)N * 128 * 2;  // GEMM A operand (bf16)
    unsigned short* xs = (unsigned short*)p; p += (size_t)N * 128 * 2;  // GEMM output (bf16)
    float* agg   = (float*)p;               p += (size_t)N * 128 * 4;
    float* h1    = (float*)p;               p += (size_t)N * 128 * 4;
    float* gsum  = (float*)p;               p += 128 * 4;
    float* gsq   = (float*)p;               p += 128 * 4;
    float* scale = (float*)p;               p += 128 * 4;
    float* shift = (float*)p;               p += 128 * 4;
    unsigned short* Wp1 = (unsigned short*)p; p += 16384 * 2;
    unsigned short* Wp2 = (unsigned short*)p; p += 16384 * 2;
    unsigned short* Wp3 = (unsigned short*)p; p += 8192 * 2;
    int*   ccnt  = (int*)p;                 p += 256 * 4;
    int*   cbase = (int*)p;                 p += 260 * 4;   // 257 used
    int*   ccur  = (int*)p;                 p += 256 * 4;
    unsigned int* pairs = (unsigned int*)p; p += (size_t)E * 4;
    int*   rs    = (int*)p;                 p += (size_t)(N + 16) * 4;
    int*   eb    = (int*)p;                 p += (size_t)E * 4;

    const int B = 256;
    const int gT    = (N + 63) / 64;
    const int g4    = (N * 128 / 4 + B - 1) / B;
    const int gEchk = (E + 4095) / 4096;     // 4096-edge chunks
    const int gN256 = (N + 255) / 256;       // coarse buckets / fine blocks
    const float inv_n = 1.0f / (float)N;

    // ---- CSR build (2-level counting sort) + weight packing ----
    hipMemsetAsync(ccnt, 0, 256 * 4, stream);
    k_hist_coarse<<<gEchk, B, 0, stream>>>(dst, ccnt, E);
    k_scan_coarse<<<1, B, 0, stream>>>(ccnt, cbase, ccur);
    k_partition<<<gEchk, B, 0, stream>>>(src, dst, ccur, pairs, E);
    k_fine<<<gN256, B, 0, stream>>>(pairs, cbase, rs, eb, dinv, N, E);
    k_packW<<<8, B, 0, stream>>>(W1, Wp1, 128);
    k_packW<<<8, B, 0, stream>>>(W2, Wp2, 128);
    k_packW<<<4, B, 0, stream>>>(W3, Wp3, 64);

    // ---- layer 1: xs = (bf16(x)@W1)*dinv; agg = gather ----
    k_gemm_mfma128_f32<<<gT, B, 0, stream>>>(x, Wp1, xs, dinv, N);
    k_gather128<<<(N + 7) / 8, B, 0, stream>>>(agg, xs, rs, eb, dinv, N);
    hipMemsetAsync(gsum, 0, 2 * 128 * 4, stream);
    k_stats<<<512, B, 0, stream>>>(agg, gsum, gsq, N);
    k_finalize<<<1, 128, 0, stream>>>(gsum, gsq, g1, be1, scale, shift, inv_n);

    // ---- layer 2: h1 = relu(bn(agg))+x (fp32 + bf16); xs = (h1@W2)*dinv; agg = gather ----
    k_bnrelu_dual<<<g4, B, 0, stream>>>(h1, xb, agg, x, scale, shift, N * 128 / 4);
    k_gemm_mfma128<<<gT, B, 0, stream>>>(xb, Wp2, xs, dinv, N);
    k_gather128<<<(N + 7) / 8, B, 0, stream>>>(agg, xs, rs, eb, dinv, N);
    hipMemsetAsync(gsum, 0, 2 * 128 * 4, stream);
    k_stats<<<512, B, 0, stream>>>(agg, gsum, gsq, N);
    k_finalize<<<1, 128, 0, stream>>>(gsum, gsq, g2, be2, scale, shift, inv_n);

    // ---- layer 3: h2 = relu(bn(agg))+h1 (bf16 only); xs = (h2@W3)*dinv; out = gather+b3 ----
    k_bnrelu_bf<<<g4, B, 0, stream>>>(xb, agg, h1, scale, shift, N * 128 / 4);
    k_gemm_mfma64<<<gT, B, 0, stream>>>(xb, Wp3, xs, dinv, N);
    k_gather64_bias<<<(N + 15) / 16, B, 0, stream>>>(out, xs, rs, eb, dinv, b3, N);
}